// Round 1
// baseline (3302.938 us; speedup 1.0000x reference)
//
#include <hip/hip_runtime.h>
#include <hip/hip_bf16.h>
#include <cstdint>

#define DMODEL 1024
#define DHALF  512
#define DINNER 1024
#define DSTATE 16
#define DTRANK 32
#define LSEQ   4096
#define BBATCH 2
#define MROWS  (BBATCH*LSEQ)   // 8192

using bf16 = __bf16;
using bf16x8 = __attribute__((ext_vector_type(8))) __bf16;
using f32x4  = __attribute__((ext_vector_type(4))) float;

__device__ __forceinline__ float sigmoidf_(float x) { return 1.f / (1.f + __expf(-x)); }
__device__ __forceinline__ float softplusf_(float x) { return fmaxf(x, 0.f) + log1pf(__expf(-fabsf(x))); }

// ---------------------------------------------------------------- LayerNorm
__global__ __launch_bounds__(256) void ln_kernel(
    const float* __restrict__ x, const float* __restrict__ w,
    const float* __restrict__ b, bf16* __restrict__ xn)
{
    const int row = blockIdx.x;
    const int tid = threadIdx.x;
    const float4 v = *(const float4*)&x[(size_t)row * DMODEL + tid * 4];
    float s  = v.x + v.y + v.z + v.w;
    float s2 = v.x * v.x + v.y * v.y + v.z * v.z + v.w * v.w;
#pragma unroll
    for (int off = 1; off < 64; off <<= 1) {
        s  += __shfl_xor(s, off);
        s2 += __shfl_xor(s2, off);
    }
    __shared__ float red[8];
    const int wid = tid >> 6;
    if ((tid & 63) == 0) { red[wid] = s; red[4 + wid] = s2; }
    __syncthreads();
    s  = red[0] + red[1] + red[2] + red[3];
    s2 = red[4] + red[5] + red[6] + red[7];
    const float mu   = s * (1.f / DMODEL);
    const float var  = s2 * (1.f / DMODEL) - mu * mu;
    const float rstd = rsqrtf(var + 1e-5f);
    const float4 wv = *(const float4*)&w[tid * 4];
    const float4 bv = *(const float4*)&b[tid * 4];
    union { bf16 o[4]; uint2 u; } pk;
    pk.o[0] = (bf16)((v.x - mu) * rstd * wv.x + bv.x);
    pk.o[1] = (bf16)((v.y - mu) * rstd * wv.y + bv.y);
    pk.o[2] = (bf16)((v.z - mu) * rstd * wv.z + bv.z);
    pk.o[3] = (bf16)((v.w - mu) * rstd * wv.w + bv.w);
    *(uint2*)&xn[(size_t)row * DMODEL + tid * 4] = pk.u;
}

// ------------------------------------------------------- weight fp32->bf16
__global__ __launch_bounds__(256) void cvt_weights_kernel(
    const float* __restrict__ s0, const float* __restrict__ s1,
    const float* __restrict__ s2, const float* __restrict__ s3,
    const float* __restrict__ s4, const float* __restrict__ s5,
    const float* __restrict__ s6, const float* __restrict__ s7,
    bf16* __restrict__ d0, bf16* __restrict__ d1, bf16* __restrict__ d2,
    bf16* __restrict__ d3, bf16* __restrict__ d4, bf16* __restrict__ d5,
    bf16* __restrict__ d6, bf16* __restrict__ d7)
{
    const size_t gid = ((size_t)blockIdx.x * 256 + threadIdx.x) * 4;
    const float* s; bf16* dst; size_t off;
    if      (gid < 1048576) { s = s0; dst = d0; off = gid; }
    else if (gid < 2097152) { s = s1; dst = d1; off = gid - 1048576; }
    else if (gid < 2162688) { s = s2; dst = d2; off = gid - 2097152; }
    else if (gid < 2228224) { s = s3; dst = d3; off = gid - 2162688; }
    else if (gid < 2752512) { s = s4; dst = d4; off = gid - 2228224; }
    else if (gid < 3276800) { s = s5; dst = d5; off = gid - 2752512; }
    else if (gid < 3309568) { s = s6; dst = d6; off = gid - 3276800; }
    else if (gid < 3342336) { s = s7; dst = d7; off = gid - 3309568; }
    else return;
    const float4 v = *(const float4*)&s[off];
    union { bf16 o[4]; uint2 u; } pk;
    pk.o[0] = (bf16)v.x; pk.o[1] = (bf16)v.y; pk.o[2] = (bf16)v.z; pk.o[3] = (bf16)v.w;
    *(uint2*)&dst[off] = pk.u;
}

// ----------------------------------------------------------------- GEMM
// C[m,n] = sum_k A[m,k] * W[n,k]   (A: [M,lda] bf16, W: [N,ldw] bf16 row-major)
// EPI 0: bf16 store     EPI 1: f32 + bf16 dual store
// EPI 2: softplus(v+bias[col]) f32    EPI 3: v + residual, f32
template<int BM, int BN, int WTM, int WTN, int EPI>
__global__ __launch_bounds__(256) void gemm_k(
    const bf16* __restrict__ A0, long aDirStride, int lda,
    const bf16* __restrict__ W0, const bf16* __restrict__ W1, int ldw,
    void* __restrict__ C0, long cDirStride, int ldc,
    void* __restrict__ C1, long c1DirStride,
    const float* __restrict__ X0, const float* __restrict__ X1,
    int K)
{
    constexpr int WGN = BN / (WTN * 16);
    constexpr int PAD = 40;               // 80B rows: 16B aligned, ~2-way banks
    static_assert((BM * 32) % 2048 == 0 && (BN * 32) % 2048 == 0, "tile");
    __shared__ alignas(16) bf16 As[BM][PAD];
    __shared__ alignas(16) bf16 Bs[BN][PAD];
    const int tid = threadIdx.x;
    const int wid = tid >> 6, lane = tid & 63;
    const int wr = wid / WGN, wc = wid % WGN;
    const int bx = blockIdx.x, by = blockIdx.y, bz = blockIdx.z;
    const bf16* A = A0 + (long)bz * aDirStride + (long)by * BM * lda;
    const bf16* W = (bz ? W1 : W0) + (long)bx * BN * ldw;
    f32x4 acc[WTM][WTN] = {};
    for (int k0 = 0; k0 < K; k0 += 32) {
        constexpr int AP = BM * 32 / 2048;
#pragma unroll
        for (int p = 0; p < AP; ++p) {
            const int idx = (tid + p * 256) * 8;
            const int r = idx >> 5, c = idx & 31;
            *(bf16x8*)&As[r][c] = *(const bf16x8*)&A[(long)r * lda + k0 + c];
        }
        constexpr int BP = BN * 32 / 2048;
#pragma unroll
        for (int p = 0; p < BP; ++p) {
            const int idx = (tid + p * 256) * 8;
            const int r = idx >> 5, c = idx & 31;
            *(bf16x8*)&Bs[r][c] = *(const bf16x8*)&W[(long)r * ldw + k0 + c];
        }
        __syncthreads();
        const int rA = lane & 15, kO = (lane >> 4) * 8;
        bf16x8 af[WTM], bw[WTN];
#pragma unroll
        for (int i = 0; i < WTM; ++i) af[i] = *(const bf16x8*)&As[wr * WTM * 16 + i * 16 + rA][kO];
#pragma unroll
        for (int j = 0; j < WTN; ++j) bw[j] = *(const bf16x8*)&Bs[wc * WTN * 16 + j * 16 + rA][kO];
#pragma unroll
        for (int i = 0; i < WTM; ++i)
#pragma unroll
            for (int j = 0; j < WTN; ++j)
                acc[i][j] = __builtin_amdgcn_mfma_f32_16x16x32_bf16(af[i], bw[j], acc[i][j], 0, 0, 0);
        __syncthreads();
    }
    const int rl = (lane >> 4) * 4, cl = lane & 15;
    const int rowBase = by * BM + wr * WTM * 16;
    const int colBase = bx * BN + wc * WTN * 16;
#pragma unroll
    for (int i = 0; i < WTM; ++i)
#pragma unroll
        for (int j = 0; j < WTN; ++j) {
#pragma unroll
            for (int r = 0; r < 4; ++r) {
                const int row = rowBase + i * 16 + rl + r;
                const int col = colBase + j * 16 + cl;
                const float v = acc[i][j][r];
                if constexpr (EPI == 0) {
                    ((bf16*)C0 + (long)bz * cDirStride)[(long)row * ldc + col] = (bf16)v;
                } else if constexpr (EPI == 1) {
                    ((float*)C0 + (long)bz * cDirStride)[(long)row * ldc + col] = v;
                    ((bf16*)C1 + (long)bz * c1DirStride)[(long)row * ldc + col] = (bf16)v;
                } else if constexpr (EPI == 2) {
                    const float* bias = bz ? X1 : X0;
                    ((float*)C0 + (long)bz * cDirStride)[(long)row * ldc + col] =
                        softplusf_(v + bias[col]);
                } else {
                    const long idx = (long)row * ldc + col;
                    ((float*)C0 + (long)bz * cDirStride)[idx] = v + (X0 + (long)bz * cDirStride)[idx];
                }
            }
        }
}

// --------------------------------------------------- depthwise conv4 + SiLU
// fwd: out[t] = silu(b + sum_j w[j]*x[t-3+j]); bwd: out[s] = silu(b + sum_j w[j]*x[s+3-j])
__global__ __launch_bounds__(256) void conv_silu_kernel(
    const bf16* __restrict__ xz, bf16* __restrict__ xc,
    const float* __restrict__ cwF, const float* __restrict__ cbF,
    const float* __restrict__ cwB, const float* __restrict__ cbB)
{
    const size_t gid = (size_t)blockIdx.x * 256 + threadIdx.x;
    const int d = (int)(gid & (DINNER - 1));
    const size_t m = (gid >> 10) & (MROWS - 1);
    const int dir = (int)(gid >> 23);
    const int t = (int)(m & (LSEQ - 1));
    const float* cw = dir ? cwB : cwF;
    const float* cb = dir ? cbB : cbF;
    const bf16* src = xz + (size_t)dir * MROWS * 2048 + (m - (size_t)t) * 2048 + d;
    float acc = cb[d];
    if (!dir) {
#pragma unroll
        for (int j = 0; j < 4; ++j) {
            const int ts = t - 3 + j;
            if (ts >= 0) acc = fmaf(cw[d * 4 + j], (float)src[(size_t)ts * 2048], acc);
        }
    } else {
#pragma unroll
        for (int j = 0; j < 4; ++j) {
            const int ts = t + 3 - j;
            if (ts < LSEQ) acc = fmaf(cw[d * 4 + j], (float)src[(size_t)ts * 2048], acc);
        }
    }
    const float s = acc * sigmoidf_(acc);
    xc[(size_t)dir * MROWS * DINNER + m * DINNER + d] = (bf16)s;
}

// -------------------------------------------------------------- selective scan
// lane = (channel_local c = lane>>4, state n = lane&15); wave = 4 channels
__global__ __launch_bounds__(256) void scan_kernel(
    const float* __restrict__ dt, const bf16* __restrict__ xc,
    const float* __restrict__ xdbl, const bf16* __restrict__ xz,
    bf16* __restrict__ yg,
    const float* __restrict__ AlogF, const float* __restrict__ AlogB,
    const float* __restrict__ DF, const float* __restrict__ DB)
{
    const int bx = blockIdx.x;                // 256 blocks
    const int dir = bx >> 7, b = (bx >> 6) & 1, cg = bx & 63;
    const int tid = threadIdx.x;
    const int wid = tid >> 6, lane = tid & 63;
    const int cl = lane >> 4, n = lane & 15;
    const int d = cg * 16 + wid * 4 + cl;
    const float* Alog = dir ? AlogB : AlogF;
    const float* Dw = dir ? DB : DF;
    const float a_dn = -__expf(Alog[d * DSTATE + n]);
    const float Dv = Dw[d];
    const size_t base1 = (size_t)dir * MROWS * DINNER + (size_t)b * LSEQ * DINNER;
    const size_t base64 = (size_t)dir * MROWS * 64 + (size_t)b * LSEQ * 64;
    const size_t baseZ = (size_t)dir * MROWS * 2048 + (size_t)b * LSEQ * 2048;
    const int t0 = dir ? (LSEQ - 1) : 0;
    const int stp = dir ? -1 : 1;
    const float* pdt = dt + base1 + (size_t)t0 * DINNER + d;
    const bf16* pxc = xc + base1 + (size_t)t0 * DINNER + d;
    const float* pB = xdbl + base64 + (size_t)t0 * 64 + 32 + n;
    const float* pC = pB + 16;
    const bf16* pz = xz + baseZ + (size_t)t0 * 2048 + 1024 + d;
    bf16* pyg = yg + base1 + (size_t)t0 * DINNER + d;
    const long s1 = (long)stp * DINNER, s64 = (long)stp * 64, sZ = (long)stp * 2048;
    float h = 0.f;
#pragma unroll 2
    for (int ti = 0; ti < LSEQ; ++ti) {
        const float dtv = *pdt;
        const float u = (float)*pxc;
        const float Bv = *pB;
        const float Cv = *pC;
        const float dA = __expf(dtv * a_dn);
        h = fmaf(h, dA, dtv * u * Bv);
        float y = h * Cv;
        y += __shfl_xor(y, 1); y += __shfl_xor(y, 2);
        y += __shfl_xor(y, 4); y += __shfl_xor(y, 8);
        if (n == 0) {
            const float z = (float)*pz;
            const float o = (y + Dv * u) * (z * sigmoidf_(z));
            *pyg = (bf16)o;
        }
        pdt += s1; pxc += s1; pB += s64; pC += s64; pz += sZ; pyg += s1;
    }
}

// ------------------------------------------------------------------- launch
extern "C" void kernel_launch(void* const* d_in, const int* in_sizes, int n_in,
                              void* d_out, int out_size, void* d_ws, size_t ws_size,
                              hipStream_t stream)
{
    const float* x      = (const float*)d_in[0];
    const float* norm_w = (const float*)d_in[1];
    const float* norm_b = (const float*)d_in[2];
    const float* ipF  = (const float*)d_in[3];
    const float* cwF  = (const float*)d_in[4];
    const float* cbF  = (const float*)d_in[5];
    const float* xpF  = (const float*)d_in[6];
    const float* dtwF = (const float*)d_in[7];
    const float* dtbF = (const float*)d_in[8];
    const float* AlF  = (const float*)d_in[9];
    const float* DF   = (const float*)d_in[10];
    const float* opF  = (const float*)d_in[11];
    const float* ipB  = (const float*)d_in[12];
    const float* cwB  = (const float*)d_in[13];
    const float* cbB  = (const float*)d_in[14];
    const float* xpB  = (const float*)d_in[15];
    const float* dtwB = (const float*)d_in[16];
    const float* dtbB = (const float*)d_in[17];
    const float* AlB  = (const float*)d_in[18];
    const float* DB   = (const float*)d_in[19];
    const float* opB  = (const float*)d_in[20];

    char* ws = (char*)d_ws;
    size_t off = 0;
    auto alloc = [&](size_t bytes) -> void* {
        void* p = ws + off;
        off += (bytes + 255) & ~(size_t)255;
        return p;
    };
    bf16*  xn      = (bf16*)alloc((size_t)MROWS * DMODEL * 2);
    bf16*  win     = (bf16*)alloc((size_t)2 * 2048 * 512 * 2);
    bf16*  wxp     = (bf16*)alloc((size_t)2 * 64 * 1024 * 2);
    bf16*  wop     = (bf16*)alloc((size_t)2 * 512 * 1024 * 2);
    bf16*  wdt     = (bf16*)alloc((size_t)2 * 1024 * 32 * 2);
    bf16*  xz      = (bf16*)alloc((size_t)2 * MROWS * 2048 * 2);
    bf16*  xc      = (bf16*)alloc((size_t)2 * MROWS * 1024 * 2);
    float* xdbl    = (float*)alloc((size_t)2 * MROWS * 64 * 4);
    bf16*  xdbl_bf = (bf16*)alloc((size_t)2 * MROWS * 64 * 2);
    float* dt      = (float*)alloc((size_t)2 * MROWS * 1024 * 4);
    bf16*  yg      = (bf16*)alloc((size_t)2 * MROWS * 1024 * 2);

    cvt_weights_kernel<<<3264, 256, 0, stream>>>(
        ipF, ipB, xpF, xpB, opF, opB, dtwF, dtwB,
        win, win + 2048 * 512, wxp, wxp + 64 * 1024,
        wop, wop + 512 * 1024, wdt, wdt + 1024 * 32);

    ln_kernel<<<MROWS, 256, 0, stream>>>(x, norm_w, norm_b, xn);

    // in_proj: [8192,512] x [2048,512]^T -> xz bf16 [dir][8192][2048]
    gemm_k<128, 128, 4, 4, 0><<<dim3(16, 64, 2), 256, 0, stream>>>(
        xn, 512, DMODEL, win, win + 2048 * 512, 512,
        xz, (long)MROWS * 2048, 2048, nullptr, 0, nullptr, nullptr, 512);

    conv_silu_kernel<<<65536, 256, 0, stream>>>(xz, xc, cwF, cbF, cwB, cbB);

    // x_proj: [8192,1024] x [64,1024]^T -> x_dbl f32 + bf16 shadow
    gemm_k<128, 64, 4, 2, 1><<<dim3(1, 64, 2), 256, 0, stream>>>(
        xc, (long)MROWS * 1024, 1024, wxp, wxp + 64 * 1024, 1024,
        xdbl, (long)MROWS * 64, 64, xdbl_bf, (long)MROWS * 64, nullptr, nullptr, 1024);

    // dt_proj: [8192,32] x [1024,32]^T -> softplus(+bias) f32
    gemm_k<128, 128, 4, 4, 2><<<dim3(8, 64, 2), 256, 0, stream>>>(
        xdbl_bf, (long)MROWS * 64, 64, wdt, wdt + 1024 * 32, 32,
        dt, (long)MROWS * 1024, 1024, nullptr, 0, dtbF, dtbB, 32);

    scan_kernel<<<256, 256, 0, stream>>>(dt, xc, xdbl, xz, yg, AlF, AlB, DF, DB);

    // out_proj + residual: [8192,1024] x [512,1024]^T -> d_out[row][dir*512+col]
    gemm_k<128, 128, 4, 4, 3><<<dim3(4, 64, 2), 256, 0, stream>>>(
        yg, (long)MROWS * 1024, 1024, wop, wop + 512 * 1024, 1024,
        d_out, 512, 1024, nullptr, 0, x, nullptr, 1024);
}

// Round 2
// 891.212 us; speedup vs baseline: 3.7061x; 3.7061x over previous
//
#include <hip/hip_runtime.h>
#include <hip/hip_bf16.h>
#include <cstdint>

#define DMODEL 1024
#define DHALF  512
#define DINNER 1024
#define DSTATE 16
#define DTRANK 32
#define LSEQ   4096
#define BBATCH 2
#define MROWS  (BBATCH*LSEQ)   // 8192
#define SCH    64              // scan chunks
#define SCT    64              // steps per chunk (SCH*SCT == LSEQ)

using bf16 = __bf16;
using bf16x8 = __attribute__((ext_vector_type(8))) __bf16;
using f32x4  = __attribute__((ext_vector_type(4))) float;

__device__ __forceinline__ float sigmoidf_(float x) { return 1.f / (1.f + __expf(-x)); }
__device__ __forceinline__ float softplusf_(float x) { return fmaxf(x, 0.f) + log1pf(__expf(-fabsf(x))); }

// ---------------------------------------------------------------- LayerNorm
__global__ __launch_bounds__(256) void ln_kernel(
    const float* __restrict__ x, const float* __restrict__ w,
    const float* __restrict__ b, bf16* __restrict__ xn)
{
    const int row = blockIdx.x;
    const int tid = threadIdx.x;
    const float4 v = *(const float4*)&x[(size_t)row * DMODEL + tid * 4];
    float s  = v.x + v.y + v.z + v.w;
    float s2 = v.x * v.x + v.y * v.y + v.z * v.z + v.w * v.w;
#pragma unroll
    for (int off = 1; off < 64; off <<= 1) {
        s  += __shfl_xor(s, off);
        s2 += __shfl_xor(s2, off);
    }
    __shared__ float red[8];
    const int wid = tid >> 6;
    if ((tid & 63) == 0) { red[wid] = s; red[4 + wid] = s2; }
    __syncthreads();
    s  = red[0] + red[1] + red[2] + red[3];
    s2 = red[4] + red[5] + red[6] + red[7];
    const float mu   = s * (1.f / DMODEL);
    const float var  = s2 * (1.f / DMODEL) - mu * mu;
    const float rstd = rsqrtf(var + 1e-5f);
    const float4 wv = *(const float4*)&w[tid * 4];
    const float4 bv = *(const float4*)&b[tid * 4];
    union { bf16 o[4]; uint2 u; } pk;
    pk.o[0] = (bf16)((v.x - mu) * rstd * wv.x + bv.x);
    pk.o[1] = (bf16)((v.y - mu) * rstd * wv.y + bv.y);
    pk.o[2] = (bf16)((v.z - mu) * rstd * wv.z + bv.z);
    pk.o[3] = (bf16)((v.w - mu) * rstd * wv.w + bv.w);
    *(uint2*)&xn[(size_t)row * DMODEL + tid * 4] = pk.u;
}

// ------------------------------------------------------- weight fp32->bf16
__global__ __launch_bounds__(256) void cvt_weights_kernel(
    const float* __restrict__ s0, const float* __restrict__ s1,
    const float* __restrict__ s2, const float* __restrict__ s3,
    const float* __restrict__ s4, const float* __restrict__ s5,
    const float* __restrict__ s6, const float* __restrict__ s7,
    bf16* __restrict__ d0, bf16* __restrict__ d1, bf16* __restrict__ d2,
    bf16* __restrict__ d3, bf16* __restrict__ d4, bf16* __restrict__ d5,
    bf16* __restrict__ d6, bf16* __restrict__ d7)
{
    const size_t gid = ((size_t)blockIdx.x * 256 + threadIdx.x) * 4;
    const float* s; bf16* dst; size_t off;
    if      (gid < 1048576) { s = s0; dst = d0; off = gid; }
    else if (gid < 2097152) { s = s1; dst = d1; off = gid - 1048576; }
    else if (gid < 2162688) { s = s2; dst = d2; off = gid - 2097152; }
    else if (gid < 2228224) { s = s3; dst = d3; off = gid - 2162688; }
    else if (gid < 2752512) { s = s4; dst = d4; off = gid - 2228224; }
    else if (gid < 3276800) { s = s5; dst = d5; off = gid - 2752512; }
    else if (gid < 3309568) { s = s6; dst = d6; off = gid - 3276800; }
    else if (gid < 3342336) { s = s7; dst = d7; off = gid - 3309568; }
    else return;
    const float4 v = *(const float4*)&s[off];
    union { bf16 o[4]; uint2 u; } pk;
    pk.o[0] = (bf16)v.x; pk.o[1] = (bf16)v.y; pk.o[2] = (bf16)v.z; pk.o[3] = (bf16)v.w;
    *(uint2*)&dst[off] = pk.u;
}

// ----------------------------------------------------------------- GEMM
// C[m,n] = sum_k A[m,k] * W[n,k]   (A: [M,lda] bf16, W: [N,ldw] bf16 row-major)
// EPI 0: bf16 store     EPI 1: f32 + bf16 dual store
// EPI 2: softplus(v+bias[col]) f32    EPI 3: v + residual, f32
template<int BM, int BN, int WTM, int WTN, int EPI>
__global__ __launch_bounds__(256) void gemm_k(
    const bf16* __restrict__ A0, long aDirStride, int lda,
    const bf16* __restrict__ W0, const bf16* __restrict__ W1, int ldw,
    void* __restrict__ C0, long cDirStride, int ldc,
    void* __restrict__ C1, long c1DirStride,
    const float* __restrict__ X0, const float* __restrict__ X1,
    int K)
{
    constexpr int WGN = BN / (WTN * 16);
    constexpr int PAD = 40;               // 80B rows: 16B aligned, ~2-way banks
    static_assert((BM * 32) % 2048 == 0 && (BN * 32) % 2048 == 0, "tile");
    __shared__ alignas(16) bf16 As[BM][PAD];
    __shared__ alignas(16) bf16 Bs[BN][PAD];
    const int tid = threadIdx.x;
    const int wid = tid >> 6, lane = tid & 63;
    const int wr = wid / WGN, wc = wid % WGN;
    const int bx = blockIdx.x, by = blockIdx.y, bz = blockIdx.z;
    const bf16* A = A0 + (long)bz * aDirStride + (long)by * BM * lda;
    const bf16* W = (bz ? W1 : W0) + (long)bx * BN * ldw;
    f32x4 acc[WTM][WTN] = {};
    for (int k0 = 0; k0 < K; k0 += 32) {
        constexpr int AP = BM * 32 / 2048;
#pragma unroll
        for (int p = 0; p < AP; ++p) {
            const int idx = (tid + p * 256) * 8;
            const int r = idx >> 5, c = idx & 31;
            *(bf16x8*)&As[r][c] = *(const bf16x8*)&A[(long)r * lda + k0 + c];
        }
        constexpr int BP = BN * 32 / 2048;
#pragma unroll
        for (int p = 0; p < BP; ++p) {
            const int idx = (tid + p * 256) * 8;
            const int r = idx >> 5, c = idx & 31;
            *(bf16x8*)&Bs[r][c] = *(const bf16x8*)&W[(long)r * ldw + k0 + c];
        }
        __syncthreads();
        const int rA = lane & 15, kO = (lane >> 4) * 8;
        bf16x8 af[WTM], bw[WTN];
#pragma unroll
        for (int i = 0; i < WTM; ++i) af[i] = *(const bf16x8*)&As[wr * WTM * 16 + i * 16 + rA][kO];
#pragma unroll
        for (int j = 0; j < WTN; ++j) bw[j] = *(const bf16x8*)&Bs[wc * WTN * 16 + j * 16 + rA][kO];
#pragma unroll
        for (int i = 0; i < WTM; ++i)
#pragma unroll
            for (int j = 0; j < WTN; ++j)
                acc[i][j] = __builtin_amdgcn_mfma_f32_16x16x32_bf16(af[i], bw[j], acc[i][j], 0, 0, 0);
        __syncthreads();
    }
    const int rl = (lane >> 4) * 4, cl = lane & 15;
    const int rowBase = by * BM + wr * WTM * 16;
    const int colBase = bx * BN + wc * WTN * 16;
#pragma unroll
    for (int i = 0; i < WTM; ++i)
#pragma unroll
        for (int j = 0; j < WTN; ++j) {
#pragma unroll
            for (int r = 0; r < 4; ++r) {
                const int row = rowBase + i * 16 + rl + r;
                const int col = colBase + j * 16 + cl;
                const float v = acc[i][j][r];
                if constexpr (EPI == 0) {
                    ((bf16*)C0 + (long)bz * cDirStride)[(long)row * ldc + col] = (bf16)v;
                } else if constexpr (EPI == 1) {
                    ((float*)C0 + (long)bz * cDirStride)[(long)row * ldc + col] = v;
                    ((bf16*)C1 + (long)bz * c1DirStride)[(long)row * ldc + col] = (bf16)v;
                } else if constexpr (EPI == 2) {
                    const float* bias = bz ? X1 : X0;
                    ((float*)C0 + (long)bz * cDirStride)[(long)row * ldc + col] =
                        softplusf_(v + bias[col]);
                } else {
                    const long idx = (long)row * ldc + col;
                    ((float*)C0 + (long)bz * cDirStride)[idx] = v + (X0 + (long)bz * cDirStride)[idx];
                }
            }
        }
}

// --------------------------------------------------- depthwise conv4 + SiLU
__global__ __launch_bounds__(256) void conv_silu_kernel(
    const bf16* __restrict__ xz, bf16* __restrict__ xc,
    const float* __restrict__ cwF, const float* __restrict__ cbF,
    const float* __restrict__ cwB, const float* __restrict__ cbB)
{
    const size_t gid = (size_t)blockIdx.x * 256 + threadIdx.x;
    const int d = (int)(gid & (DINNER - 1));
    const size_t m = (gid >> 10) & (MROWS - 1);
    const int dir = (int)(gid >> 23);
    const int t = (int)(m & (LSEQ - 1));
    const float* cw = dir ? cwB : cwF;
    const float* cb = dir ? cbB : cbF;
    const bf16* src = xz + (size_t)dir * MROWS * 2048 + (m - (size_t)t) * 2048 + d;
    float acc = cb[d];
    if (!dir) {
#pragma unroll
        for (int j = 0; j < 4; ++j) {
            const int ts = t - 3 + j;
            if (ts >= 0) acc = fmaf(cw[d * 4 + j], (float)src[(size_t)ts * 2048], acc);
        }
    } else {
#pragma unroll
        for (int j = 0; j < 4; ++j) {
            const int ts = t + 3 - j;
            if (ts < LSEQ) acc = fmaf(cw[d * 4 + j], (float)src[(size_t)ts * 2048], acc);
        }
    }
    const float s = acc * sigmoidf_(acc);
    xc[(size_t)dir * MROWS * DINNER + m * DINNER + d] = (bf16)s;
}

// ------------------------------------------------- chunked selective scan
// thread = (sb, chunk, d, n). chunk-local scan from h=0; stores h_end, prod(dA).
__global__ __launch_bounds__(256) void scan_part1(
    const float* __restrict__ dt, const bf16* __restrict__ xc,
    const float* __restrict__ xdbl,
    float* __restrict__ hend, float* __restrict__ prodA,
    const float* __restrict__ AlogF, const float* __restrict__ AlogB)
{
    const int cg = blockIdx.x;      // 64 channel groups of 16
    const int chunk = blockIdx.y;   // SCH
    const int sb = blockIdx.z;      // dir*2 + b
    const int dir = sb >> 1, b = sb & 1;
    const int tid = threadIdx.x;
    const int wid = tid >> 6, lane = tid & 63;
    const int cl = lane >> 4, n = lane & 15;
    const int d = cg * 16 + wid * 4 + cl;
    const float* Alog = dir ? AlogB : AlogF;
    const float a_dn = -__expf(Alog[d * DSTATE + n]);
    const size_t base1 = (size_t)dir * MROWS * DINNER + (size_t)b * LSEQ * DINNER;
    const size_t base64 = (size_t)dir * MROWS * 64 + (size_t)b * LSEQ * 64;
    const int t0 = dir ? (LSEQ - 1) : 0;
    const int stp = dir ? -1 : 1;
    const int ts = t0 + stp * (chunk * SCT);
    const float* pdt = dt + base1 + (size_t)ts * DINNER + d;
    const bf16* pxc = xc + base1 + (size_t)ts * DINNER + d;
    const float* pB = xdbl + base64 + (size_t)ts * 64 + 32 + n;
    const long s1 = (long)stp * DINNER, s64 = (long)stp * 64;
    float h = 0.f, prod = 1.f;
#pragma unroll 8
    for (int i = 0; i < SCT; ++i) {
        const float dtv = *pdt;
        const float u = (float)*pxc;
        const float Bv = *pB;
        const float dA = __expf(dtv * a_dn);
        prod *= dA;
        h = fmaf(h, dA, dtv * u * Bv);
        pdt += s1; pxc += s1; pB += s64;
    }
    const size_t o = ((size_t)sb * SCH + chunk) * 16384 + (size_t)cg * 256 + wid * 64 + lane;
    hend[o] = h;
    prodA[o] = prod;
}

// combine chunk summaries; in-place: hend[c] becomes h_in for chunk c
__global__ __launch_bounds__(256) void scan_part2(
    float* __restrict__ hend, const float* __restrict__ prodA)
{
    const size_t gid = (size_t)blockIdx.x * 256 + threadIdx.x;  // 65536 = 4*16384
    const int sb = (int)(gid >> 14);
    const size_t dn = gid & 16383;
    float h = 0.f;
    size_t idx = (size_t)sb * SCH * 16384 + dn;
#pragma unroll 8
    for (int c = 0; c < SCH; ++c) {
        const float pe = prodA[idx];
        const float he = hend[idx];
        hend[idx] = h;
        h = fmaf(pe, h, he);
        idx += 16384;
    }
}

// final pass: chunk scan from correct h_in; y = sum_n h*C; gate with silu(z)
__global__ __launch_bounds__(256) void scan_part3(
    const float* __restrict__ dt, const bf16* __restrict__ xc,
    const float* __restrict__ xdbl, const bf16* __restrict__ xz,
    const float* __restrict__ hin, bf16* __restrict__ yg,
    const float* __restrict__ AlogF, const float* __restrict__ AlogB,
    const float* __restrict__ DF, const float* __restrict__ DB)
{
    const int cg = blockIdx.x;
    const int chunk = blockIdx.y;
    const int sb = blockIdx.z;
    const int dir = sb >> 1, b = sb & 1;
    const int tid = threadIdx.x;
    const int wid = tid >> 6, lane = tid & 63;
    const int cl = lane >> 4, n = lane & 15;
    const int d = cg * 16 + wid * 4 + cl;
    const float* Alog = dir ? AlogB : AlogF;
    const float* Dw = dir ? DB : DF;
    const float a_dn = -__expf(Alog[d * DSTATE + n]);
    const float Dv = Dw[d];
    const size_t base1 = (size_t)dir * MROWS * DINNER + (size_t)b * LSEQ * DINNER;
    const size_t base64 = (size_t)dir * MROWS * 64 + (size_t)b * LSEQ * 64;
    const size_t baseZ = (size_t)dir * MROWS * 2048 + (size_t)b * LSEQ * 2048;
    const int t0 = dir ? (LSEQ - 1) : 0;
    const int stp = dir ? -1 : 1;
    const int ts = t0 + stp * (chunk * SCT);
    const float* pdt = dt + base1 + (size_t)ts * DINNER + d;
    const bf16* pxc = xc + base1 + (size_t)ts * DINNER + d;
    const float* pB = xdbl + base64 + (size_t)ts * 64 + 32 + n;
    const float* pC = pB + 16;
    const bf16* pz = xz + baseZ + (size_t)ts * 2048 + 1024 + d;
    bf16* pyg = yg + base1 + (size_t)ts * DINNER + d;
    const long s1 = (long)stp * DINNER, s64 = (long)stp * 64, sZ = (long)stp * 2048;
    float h = hin[((size_t)sb * SCH + chunk) * 16384 + (size_t)cg * 256 + wid * 64 + lane];
#pragma unroll 4
    for (int i = 0; i < SCT; ++i) {
        const float dtv = *pdt;
        const float u = (float)*pxc;
        const float Bv = *pB;
        const float Cv = *pC;
        const float dA = __expf(dtv * a_dn);
        h = fmaf(h, dA, dtv * u * Bv);
        float y = h * Cv;
        y += __shfl_xor(y, 1); y += __shfl_xor(y, 2);
        y += __shfl_xor(y, 4); y += __shfl_xor(y, 8);
        if (n == 0) {
            const float z = (float)*pz;
            const float o = (y + Dv * u) * (z * sigmoidf_(z));
            *pyg = (bf16)o;
        }
        pdt += s1; pxc += s1; pB += s64; pC += s64; pz += sZ; pyg += s1;
    }
}

// ------------------------------------------------------------------- launch
extern "C" void kernel_launch(void* const* d_in, const int* in_sizes, int n_in,
                              void* d_out, int out_size, void* d_ws, size_t ws_size,
                              hipStream_t stream)
{
    const float* x      = (const float*)d_in[0];
    const float* norm_w = (const float*)d_in[1];
    const float* norm_b = (const float*)d_in[2];
    const float* ipF  = (const float*)d_in[3];
    const float* cwF  = (const float*)d_in[4];
    const float* cbF  = (const float*)d_in[5];
    const float* xpF  = (const float*)d_in[6];
    const float* dtwF = (const float*)d_in[7];
    const float* dtbF = (const float*)d_in[8];
    const float* AlF  = (const float*)d_in[9];
    const float* DF   = (const float*)d_in[10];
    const float* opF  = (const float*)d_in[11];
    const float* ipB  = (const float*)d_in[12];
    const float* cwB  = (const float*)d_in[13];
    const float* cbB  = (const float*)d_in[14];
    const float* xpB  = (const float*)d_in[15];
    const float* dtwB = (const float*)d_in[16];
    const float* dtbB = (const float*)d_in[17];
    const float* AlB  = (const float*)d_in[18];
    const float* DB   = (const float*)d_in[19];
    const float* opB  = (const float*)d_in[20];

    char* ws = (char*)d_ws;
    size_t off = 0;
    auto alloc = [&](size_t bytes) -> void* {
        void* p = ws + off;
        off += (bytes + 255) & ~(size_t)255;
        return p;
    };
    bf16*  xn      = (bf16*)alloc((size_t)MROWS * DMODEL * 2);
    bf16*  win     = (bf16*)alloc((size_t)2 * 2048 * 512 * 2);
    bf16*  wxp     = (bf16*)alloc((size_t)2 * 64 * 1024 * 2);
    bf16*  wop     = (bf16*)alloc((size_t)2 * 512 * 1024 * 2);
    bf16*  wdt     = (bf16*)alloc((size_t)2 * 1024 * 32 * 2);
    bf16*  xz      = (bf16*)alloc((size_t)2 * MROWS * 2048 * 2);
    bf16*  xc      = (bf16*)alloc((size_t)2 * MROWS * 1024 * 2);
    float* xdbl    = (float*)alloc((size_t)2 * MROWS * 64 * 4);
    bf16*  xdbl_bf = (bf16*)alloc((size_t)2 * MROWS * 64 * 2);
    float* dt      = (float*)alloc((size_t)2 * MROWS * 1024 * 4);
    bf16*  yg      = (bf16*)alloc((size_t)2 * MROWS * 1024 * 2);
    float* hend    = (float*)alloc((size_t)4 * SCH * 16384 * 4);
    float* prodA   = (float*)alloc((size_t)4 * SCH * 16384 * 4);

    cvt_weights_kernel<<<3264, 256, 0, stream>>>(
        ipF, ipB, xpF, xpB, opF, opB, dtwF, dtwB,
        win, win + 2048 * 512, wxp, wxp + 64 * 1024,
        wop, wop + 512 * 1024, wdt, wdt + 1024 * 32);

    ln_kernel<<<MROWS, 256, 0, stream>>>(x, norm_w, norm_b, xn);

    // in_proj: [8192,512] x [2048,512]^T -> xz bf16 [dir][8192][2048]
    gemm_k<128, 128, 4, 4, 0><<<dim3(16, 64, 2), 256, 0, stream>>>(
        xn, 512, DMODEL, win, win + 2048 * 512, 512,
        xz, (long)MROWS * 2048, 2048, nullptr, 0, nullptr, nullptr, 512);

    conv_silu_kernel<<<65536, 256, 0, stream>>>(xz, xc, cwF, cbF, cwB, cbB);

    // x_proj: [8192,1024] x [64,1024]^T -> x_dbl f32 + bf16 shadow
    gemm_k<128, 64, 4, 2, 1><<<dim3(1, 64, 2), 256, 0, stream>>>(
        xc, (long)MROWS * 1024, 1024, wxp, wxp + 64 * 1024, 1024,
        xdbl, (long)MROWS * 64, 64, xdbl_bf, (long)MROWS * 64, nullptr, nullptr, 1024);

    // dt_proj: [8192,32] x [1024,32]^T -> softplus(+bias) f32
    gemm_k<128, 128, 4, 4, 2><<<dim3(8, 64, 2), 256, 0, stream>>>(
        xdbl_bf, (long)MROWS * 64, 64, wdt, wdt + 1024 * 32, 32,
        dt, (long)MROWS * 1024, 1024, nullptr, 0, dtbF, dtbB, 32);

    // chunked scan: 64 chunks x 64 steps
    scan_part1<<<dim3(64, SCH, 4), 256, 0, stream>>>(dt, xc, xdbl, hend, prodA, AlF, AlB);
    scan_part2<<<256, 256, 0, stream>>>(hend, prodA);
    scan_part3<<<dim3(64, SCH, 4), 256, 0, stream>>>(dt, xc, xdbl, xz, hend, yg,
                                                     AlF, AlB, DF, DB);

    // out_proj + residual: [8192,1024] x [512,1024]^T -> d_out[row][dir*512+col]
    gemm_k<128, 128, 4, 4, 3><<<dim3(4, 64, 2), 256, 0, stream>>>(
        yg, (long)MROWS * 1024, 1024, wop, wop + 512 * 1024, 1024,
        d_out, 512, 1024, nullptr, 0, x, nullptr, 1024);
}

// Round 3
// 520.409 us; speedup vs baseline: 6.3468x; 1.7125x over previous
//
#include <hip/hip_runtime.h>
#include <hip/hip_bf16.h>
#include <cstdint>

#define DMODEL 1024
#define DHALF  512
#define DINNER 1024
#define DSTATE 16
#define DTRANK 32
#define LSEQ   4096
#define BBATCH 2
#define MROWS  (BBATCH*LSEQ)   // 8192
#define SCH    64              // scan chunks
#define SCT    64              // steps per chunk (SCH*SCT == LSEQ)

using bf16 = __bf16;
using bf16x8 = __attribute__((ext_vector_type(8))) __bf16;
using f32x4  = __attribute__((ext_vector_type(4))) float;

__device__ __forceinline__ float sigmoidf_(float x) { return 1.f / (1.f + __expf(-x)); }
__device__ __forceinline__ float softplusf_(float x) { return fmaxf(x, 0.f) + log1pf(__expf(-fabsf(x))); }

// ---------------------------------------------------------------- LayerNorm
__global__ __launch_bounds__(256) void ln_kernel(
    const float* __restrict__ x, const float* __restrict__ w,
    const float* __restrict__ b, bf16* __restrict__ xn)
{
    const int row = blockIdx.x;
    const int tid = threadIdx.x;
    const float4 v = *(const float4*)&x[(size_t)row * DMODEL + tid * 4];
    float s  = v.x + v.y + v.z + v.w;
    float s2 = v.x * v.x + v.y * v.y + v.z * v.z + v.w * v.w;
#pragma unroll
    for (int off = 1; off < 64; off <<= 1) {
        s  += __shfl_xor(s, off);
        s2 += __shfl_xor(s2, off);
    }
    __shared__ float red[8];
    const int wid = tid >> 6;
    if ((tid & 63) == 0) { red[wid] = s; red[4 + wid] = s2; }
    __syncthreads();
    s  = red[0] + red[1] + red[2] + red[3];
    s2 = red[4] + red[5] + red[6] + red[7];
    const float mu   = s * (1.f / DMODEL);
    const float var  = s2 * (1.f / DMODEL) - mu * mu;
    const float rstd = rsqrtf(var + 1e-5f);
    const float4 wv = *(const float4*)&w[tid * 4];
    const float4 bv = *(const float4*)&b[tid * 4];
    union { bf16 o[4]; uint2 u; } pk;
    pk.o[0] = (bf16)((v.x - mu) * rstd * wv.x + bv.x);
    pk.o[1] = (bf16)((v.y - mu) * rstd * wv.y + bv.y);
    pk.o[2] = (bf16)((v.z - mu) * rstd * wv.z + bv.z);
    pk.o[3] = (bf16)((v.w - mu) * rstd * wv.w + bv.w);
    *(uint2*)&xn[(size_t)row * DMODEL + tid * 4] = pk.u;
}

// ------------------------------------------------------- weight fp32->bf16
__global__ __launch_bounds__(256) void cvt_weights_kernel(
    const float* __restrict__ s0, const float* __restrict__ s1,
    const float* __restrict__ s2, const float* __restrict__ s3,
    const float* __restrict__ s4, const float* __restrict__ s5,
    const float* __restrict__ s6, const float* __restrict__ s7,
    bf16* __restrict__ d0, bf16* __restrict__ d1, bf16* __restrict__ d2,
    bf16* __restrict__ d3, bf16* __restrict__ d4, bf16* __restrict__ d5,
    bf16* __restrict__ d6, bf16* __restrict__ d7)
{
    const size_t gid = ((size_t)blockIdx.x * 256 + threadIdx.x) * 4;
    const float* s; bf16* dst; size_t off;
    if      (gid < 1048576) { s = s0; dst = d0; off = gid; }
    else if (gid < 2097152) { s = s1; dst = d1; off = gid - 1048576; }
    else if (gid < 2162688) { s = s2; dst = d2; off = gid - 2097152; }
    else if (gid < 2228224) { s = s3; dst = d3; off = gid - 2162688; }
    else if (gid < 2752512) { s = s4; dst = d4; off = gid - 2228224; }
    else if (gid < 3276800) { s = s5; dst = d5; off = gid - 2752512; }
    else if (gid < 3309568) { s = s6; dst = d6; off = gid - 3276800; }
    else if (gid < 3342336) { s = s7; dst = d7; off = gid - 3309568; }
    else return;
    const float4 v = *(const float4*)&s[off];
    union { bf16 o[4]; uint2 u; } pk;
    pk.o[0] = (bf16)v.x; pk.o[1] = (bf16)v.y; pk.o[2] = (bf16)v.z; pk.o[3] = (bf16)v.w;
    *(uint2*)&dst[off] = pk.u;
}

// ----------------------------------------------------------------- GEMM
// C[m,n] = sum_k A[m,k] * W[n,k]   (A: [M,lda] bf16, W: [N,ldw] bf16 row-major)
// EPI 0: bf16 store     EPI 1: f32 + bf16 dual store
// EPI 2: softplus(v+bias[col]) f32    EPI 3: v + residual, f32
template<int BM, int BN, int WTM, int WTN, int EPI>
__global__ __launch_bounds__(256) void gemm_k(
    const bf16* __restrict__ A0, long aDirStride, int lda,
    const bf16* __restrict__ W0, const bf16* __restrict__ W1, int ldw,
    void* __restrict__ C0, long cDirStride, int ldc,
    void* __restrict__ C1, long c1DirStride,
    const float* __restrict__ X0, const float* __restrict__ X1,
    int K)
{
    constexpr int WGN = BN / (WTN * 16);
    constexpr int PAD = 40;               // 80B rows: 16B aligned, ~2-way banks
    static_assert((BM * 32) % 2048 == 0 && (BN * 32) % 2048 == 0, "tile");
    __shared__ alignas(16) bf16 As[BM][PAD];
    __shared__ alignas(16) bf16 Bs[BN][PAD];
    const int tid = threadIdx.x;
    const int wid = tid >> 6, lane = tid & 63;
    const int wr = wid / WGN, wc = wid % WGN;
    const int bx = blockIdx.x, by = blockIdx.y, bz = blockIdx.z;
    const bf16* A = A0 + (long)bz * aDirStride + (long)by * BM * lda;
    const bf16* W = (bz ? W1 : W0) + (long)bx * BN * ldw;
    f32x4 acc[WTM][WTN] = {};
    for (int k0 = 0; k0 < K; k0 += 32) {
        constexpr int AP = BM * 32 / 2048;
#pragma unroll
        for (int p = 0; p < AP; ++p) {
            const int idx = (tid + p * 256) * 8;
            const int r = idx >> 5, c = idx & 31;
            *(bf16x8*)&As[r][c] = *(const bf16x8*)&A[(long)r * lda + k0 + c];
        }
        constexpr int BP = BN * 32 / 2048;
#pragma unroll
        for (int p = 0; p < BP; ++p) {
            const int idx = (tid + p * 256) * 8;
            const int r = idx >> 5, c = idx & 31;
            *(bf16x8*)&Bs[r][c] = *(const bf16x8*)&W[(long)r * ldw + k0 + c];
        }
        __syncthreads();
        const int rA = lane & 15, kO = (lane >> 4) * 8;
        bf16x8 af[WTM], bw[WTN];
#pragma unroll
        for (int i = 0; i < WTM; ++i) af[i] = *(const bf16x8*)&As[wr * WTM * 16 + i * 16 + rA][kO];
#pragma unroll
        for (int j = 0; j < WTN; ++j) bw[j] = *(const bf16x8*)&Bs[wc * WTN * 16 + j * 16 + rA][kO];
#pragma unroll
        for (int i = 0; i < WTM; ++i)
#pragma unroll
            for (int j = 0; j < WTN; ++j)
                acc[i][j] = __builtin_amdgcn_mfma_f32_16x16x32_bf16(af[i], bw[j], acc[i][j], 0, 0, 0);
        __syncthreads();
    }
    const int rl = (lane >> 4) * 4, cl = lane & 15;
    const int rowBase = by * BM + wr * WTM * 16;
    const int colBase = bx * BN + wc * WTN * 16;
#pragma unroll
    for (int i = 0; i < WTM; ++i)
#pragma unroll
        for (int j = 0; j < WTN; ++j) {
#pragma unroll
            for (int r = 0; r < 4; ++r) {
                const int row = rowBase + i * 16 + rl + r;
                const int col = colBase + j * 16 + cl;
                const float v = acc[i][j][r];
                if constexpr (EPI == 0) {
                    ((bf16*)C0 + (long)bz * cDirStride)[(long)row * ldc + col] = (bf16)v;
                } else if constexpr (EPI == 1) {
                    ((float*)C0 + (long)bz * cDirStride)[(long)row * ldc + col] = v;
                    ((bf16*)C1 + (long)bz * c1DirStride)[(long)row * ldc + col] = (bf16)v;
                } else if constexpr (EPI == 2) {
                    const float* bias = bz ? X1 : X0;
                    ((float*)C0 + (long)bz * cDirStride)[(long)row * ldc + col] =
                        softplusf_(v + bias[col]);
                } else {
                    const long idx = (long)row * ldc + col;
                    ((float*)C0 + (long)bz * cDirStride)[idx] = v + (X0 + (long)bz * cDirStride)[idx];
                }
            }
        }
}

// --------------------------------------------------- depthwise conv4 + SiLU
__global__ __launch_bounds__(256) void conv_silu_kernel(
    const bf16* __restrict__ xz, bf16* __restrict__ xc,
    const float* __restrict__ cwF, const float* __restrict__ cbF,
    const float* __restrict__ cwB, const float* __restrict__ cbB)
{
    const size_t gid = (size_t)blockIdx.x * 256 + threadIdx.x;
    const int d = (int)(gid & (DINNER - 1));
    const size_t m = (gid >> 10) & (MROWS - 1);
    const int dir = (int)(gid >> 23);
    const int t = (int)(m & (LSEQ - 1));
    const float* cw = dir ? cwB : cwF;
    const float* cb = dir ? cbB : cbF;
    const bf16* src = xz + (size_t)dir * MROWS * 2048 + (m - (size_t)t) * 2048 + d;
    float acc = cb[d];
    if (!dir) {
#pragma unroll
        for (int j = 0; j < 4; ++j) {
            const int ts = t - 3 + j;
            if (ts >= 0) acc = fmaf(cw[d * 4 + j], (float)src[(size_t)ts * 2048], acc);
        }
    } else {
#pragma unroll
        for (int j = 0; j < 4; ++j) {
            const int ts = t + 3 - j;
            if (ts < LSEQ) acc = fmaf(cw[d * 4 + j], (float)src[(size_t)ts * 2048], acc);
        }
    }
    const float s = acc * sigmoidf_(acc);
    xc[(size_t)dir * MROWS * DINNER + m * DINNER + d] = (bf16)s;
}

// ------------------------------------------------- chunked selective scan
// lane = one channel d; all 16 states in registers. B/C rows are wave-uniform
// (scalar loads). Summary layout: [sb][chunk][d][n], n contiguous.
__global__ __launch_bounds__(256) void scan_part1(
    const float* __restrict__ dt, const bf16* __restrict__ xc,
    const float* __restrict__ xdbl,
    float* __restrict__ hend, float* __restrict__ prodA,
    const float* __restrict__ AlogF, const float* __restrict__ AlogB)
{
    const int d = blockIdx.x * 256 + threadIdx.x;
    const int chunk = blockIdx.y;
    const int sb = blockIdx.z;
    const int dir = sb >> 1, b = sb & 1;
    const float* Alog = dir ? AlogB : AlogF;
    float a[16];
#pragma unroll
    for (int n = 0; n < 16; n += 4)
        *(float4*)&a[n] = *(const float4*)&Alog[d * 16 + n];
#pragma unroll
    for (int n = 0; n < 16; ++n) a[n] = -__expf(a[n]);
    const size_t base1 = (size_t)dir * MROWS * DINNER + (size_t)b * LSEQ * DINNER;
    const size_t base64 = (size_t)dir * MROWS * 64 + (size_t)b * LSEQ * 64;
    const int t0 = dir ? (LSEQ - 1) : 0;
    const int stp = dir ? -1 : 1;
    const int ts = t0 + stp * (chunk * SCT);
    const float* pdt = dt + base1 + (size_t)ts * DINNER + d;
    const bf16* pxc = xc + base1 + (size_t)ts * DINNER + d;
    const float* pB = xdbl + base64 + (size_t)ts * 64 + 32;
    const long s1 = (long)stp * DINNER, s64 = (long)stp * 64;
    float h[16] = {};
    float sdt = 0.f;
#pragma unroll 4
    for (int i = 0; i < SCT; ++i) {
        const float dtv = *pdt;
        const float u = (float)*pxc;
        const float dtu = dtv * u;
        sdt += dtv;
        float B[16];
#pragma unroll
        for (int n = 0; n < 16; n += 4) *(float4*)&B[n] = *(const float4*)&pB[n];
#pragma unroll
        for (int n = 0; n < 16; ++n) {
            const float dA = __expf(dtv * a[n]);
            h[n] = fmaf(h[n], dA, dtu * B[n]);
        }
        pdt += s1; pxc += s1; pB += s64;
    }
    const size_t o = ((size_t)sb * SCH + chunk) * 16384 + (size_t)d * 16;
#pragma unroll
    for (int n = 0; n < 16; n += 4) *(float4*)&hend[o + n] = *(const float4*)&h[n];
    float pr[16];
#pragma unroll
    for (int n = 0; n < 16; ++n) pr[n] = __expf(a[n] * sdt);   // prod of dA over chunk
#pragma unroll
    for (int n = 0; n < 16; n += 4) *(float4*)&prodA[o + n] = *(const float4*)&pr[n];
}

// combine chunk summaries; in-place: hend[c] becomes h_in for chunk c
__global__ __launch_bounds__(256) void scan_part2(
    float* __restrict__ hend, const float* __restrict__ prodA)
{
    const size_t gid = (size_t)blockIdx.x * 256 + threadIdx.x;  // 65536 = 4*16384
    const int sb = (int)(gid >> 14);
    const size_t dn = gid & 16383;
    float h = 0.f;
    size_t idx = (size_t)sb * SCH * 16384 + dn;
#pragma unroll 8
    for (int c = 0; c < SCH; ++c) {
        const float pe = prodA[idx];
        const float he = hend[idx];
        hend[idx] = h;
        h = fmaf(pe, h, he);
        idx += 16384;
    }
}

// final pass: chunk scan from correct h_in; y = sum_n h*C; gate with silu(z)
__global__ __launch_bounds__(256) void scan_part3(
    const float* __restrict__ dt, const bf16* __restrict__ xc,
    const float* __restrict__ xdbl, const bf16* __restrict__ xz,
    const float* __restrict__ hin, bf16* __restrict__ yg,
    const float* __restrict__ AlogF, const float* __restrict__ AlogB,
    const float* __restrict__ DF, const float* __restrict__ DB)
{
    const int d = blockIdx.x * 256 + threadIdx.x;
    const int chunk = blockIdx.y;
    const int sb = blockIdx.z;
    const int dir = sb >> 1, b = sb & 1;
    const float* Alog = dir ? AlogB : AlogF;
    const float* Dw = dir ? DB : DF;
    float a[16];
#pragma unroll
    for (int n = 0; n < 16; n += 4)
        *(float4*)&a[n] = *(const float4*)&Alog[d * 16 + n];
#pragma unroll
    for (int n = 0; n < 16; ++n) a[n] = -__expf(a[n]);
    const float Dv = Dw[d];
    const size_t base1 = (size_t)dir * MROWS * DINNER + (size_t)b * LSEQ * DINNER;
    const size_t base64 = (size_t)dir * MROWS * 64 + (size_t)b * LSEQ * 64;
    const size_t baseZ = (size_t)dir * MROWS * 2048 + (size_t)b * LSEQ * 2048;
    const int t0 = dir ? (LSEQ - 1) : 0;
    const int stp = dir ? -1 : 1;
    const int ts = t0 + stp * (chunk * SCT);
    const float* pdt = dt + base1 + (size_t)ts * DINNER + d;
    const bf16* pxc = xc + base1 + (size_t)ts * DINNER + d;
    const float* pB = xdbl + base64 + (size_t)ts * 64 + 32;
    const bf16* pz = xz + baseZ + (size_t)ts * 2048 + 1024 + d;
    bf16* pyg = yg + base1 + (size_t)ts * DINNER + d;
    const long s1 = (long)stp * DINNER, s64 = (long)stp * 64, sZ = (long)stp * 2048;
    float h[16];
    const size_t o = ((size_t)sb * SCH + chunk) * 16384 + (size_t)d * 16;
#pragma unroll
    for (int n = 0; n < 16; n += 4) *(float4*)&h[n] = *(const float4*)&hin[o + n];
#pragma unroll 4
    for (int i = 0; i < SCT; ++i) {
        const float dtv = *pdt;
        const float u = (float)*pxc;
        const float dtu = dtv * u;
        float B[16], C[16];
#pragma unroll
        for (int n = 0; n < 16; n += 4) *(float4*)&B[n] = *(const float4*)&pB[n];
#pragma unroll
        for (int n = 0; n < 16; n += 4) *(float4*)&C[n] = *(const float4*)&pB[16 + n];
        float y0 = 0.f, y1 = 0.f, y2 = 0.f, y3 = 0.f;
#pragma unroll
        for (int n = 0; n < 16; n += 4) {
            float dA;
            dA = __expf(dtv * a[n]);     h[n]     = fmaf(h[n],     dA, dtu * B[n]);     y0 = fmaf(h[n],     C[n],     y0);
            dA = __expf(dtv * a[n + 1]); h[n + 1] = fmaf(h[n + 1], dA, dtu * B[n + 1]); y1 = fmaf(h[n + 1], C[n + 1], y1);
            dA = __expf(dtv * a[n + 2]); h[n + 2] = fmaf(h[n + 2], dA, dtu * B[n + 2]); y2 = fmaf(h[n + 2], C[n + 2], y2);
            dA = __expf(dtv * a[n + 3]); h[n + 3] = fmaf(h[n + 3], dA, dtu * B[n + 3]); y3 = fmaf(h[n + 3], C[n + 3], y3);
        }
        const float y = (y0 + y1) + (y2 + y3);
        const float z = (float)*pz;
        const float out = (y + Dv * u) * (z * sigmoidf_(z));
        *pyg = (bf16)out;
        pdt += s1; pxc += s1; pB += s64; pz += sZ; pyg += s1;
    }
}

// ------------------------------------------------------------------- launch
extern "C" void kernel_launch(void* const* d_in, const int* in_sizes, int n_in,
                              void* d_out, int out_size, void* d_ws, size_t ws_size,
                              hipStream_t stream)
{
    const float* x      = (const float*)d_in[0];
    const float* norm_w = (const float*)d_in[1];
    const float* norm_b = (const float*)d_in[2];
    const float* ipF  = (const float*)d_in[3];
    const float* cwF  = (const float*)d_in[4];
    const float* cbF  = (const float*)d_in[5];
    const float* xpF  = (const float*)d_in[6];
    const float* dtwF = (const float*)d_in[7];
    const float* dtbF = (const float*)d_in[8];
    const float* AlF  = (const float*)d_in[9];
    const float* DF   = (const float*)d_in[10];
    const float* opF  = (const float*)d_in[11];
    const float* ipB  = (const float*)d_in[12];
    const float* cwB  = (const float*)d_in[13];
    const float* cbB  = (const float*)d_in[14];
    const float* xpB  = (const float*)d_in[15];
    const float* dtwB = (const float*)d_in[16];
    const float* dtbB = (const float*)d_in[17];
    const float* AlB  = (const float*)d_in[18];
    const float* DB   = (const float*)d_in[19];
    const float* opB  = (const float*)d_in[20];

    char* ws = (char*)d_ws;
    size_t off = 0;
    auto alloc = [&](size_t bytes) -> void* {
        void* p = ws + off;
        off += (bytes + 255) & ~(size_t)255;
        return p;
    };
    bf16*  xn      = (bf16*)alloc((size_t)MROWS * DMODEL * 2);
    bf16*  win     = (bf16*)alloc((size_t)2 * 2048 * 512 * 2);
    bf16*  wxp     = (bf16*)alloc((size_t)2 * 64 * 1024 * 2);
    bf16*  wop     = (bf16*)alloc((size_t)2 * 512 * 1024 * 2);
    bf16*  wdt     = (bf16*)alloc((size_t)2 * 1024 * 32 * 2);
    bf16*  xz      = (bf16*)alloc((size_t)2 * MROWS * 2048 * 2);
    bf16*  xc      = (bf16*)alloc((size_t)2 * MROWS * 1024 * 2);
    float* xdbl    = (float*)alloc((size_t)2 * MROWS * 64 * 4);
    bf16*  xdbl_bf = (bf16*)alloc((size_t)2 * MROWS * 64 * 2);
    float* dt      = (float*)alloc((size_t)2 * MROWS * 1024 * 4);
    bf16*  yg      = (bf16*)alloc((size_t)2 * MROWS * 1024 * 2);
    float* hend    = (float*)alloc((size_t)4 * SCH * 16384 * 4);
    float* prodA   = (float*)alloc((size_t)4 * SCH * 16384 * 4);

    cvt_weights_kernel<<<3264, 256, 0, stream>>>(
        ipF, ipB, xpF, xpB, opF, opB, dtwF, dtwB,
        win, win + 2048 * 512, wxp, wxp + 64 * 1024,
        wop, wop + 512 * 1024, wdt, wdt + 1024 * 32);

    ln_kernel<<<MROWS, 256, 0, stream>>>(x, norm_w, norm_b, xn);

    // in_proj: [8192,512] x [2048,512]^T -> xz bf16 [dir][8192][2048]
    gemm_k<128, 128, 4, 4, 0><<<dim3(16, 64, 2), 256, 0, stream>>>(
        xn, 512, DMODEL, win, win + 2048 * 512, 512,
        xz, (long)MROWS * 2048, 2048, nullptr, 0, nullptr, nullptr, 512);

    conv_silu_kernel<<<65536, 256, 0, stream>>>(xz, xc, cwF, cbF, cwB, cbB);

    // x_proj: [8192,1024] x [64,1024]^T -> x_dbl f32 + bf16 shadow
    gemm_k<128, 64, 4, 2, 1><<<dim3(1, 64, 2), 256, 0, stream>>>(
        xc, (long)MROWS * 1024, 1024, wxp, wxp + 64 * 1024, 1024,
        xdbl, (long)MROWS * 64, 64, xdbl_bf, (long)MROWS * 64, nullptr, nullptr, 1024);

    // dt_proj: [8192,32] x [1024,32]^T -> softplus(+bias) f32
    gemm_k<128, 128, 4, 4, 2><<<dim3(8, 64, 2), 256, 0, stream>>>(
        xdbl_bf, (long)MROWS * 64, 64, wdt, wdt + 1024 * 32, 32,
        dt, (long)MROWS * 1024, 1024, nullptr, 0, dtbF, dtbB, 32);

    // chunked scan: 64 chunks x 64 steps, lane = channel
    scan_part1<<<dim3(4, SCH, 4), 256, 0, stream>>>(dt, xc, xdbl, hend, prodA, AlF, AlB);
    scan_part2<<<256, 256, 0, stream>>>(hend, prodA);
    scan_part3<<<dim3(4, SCH, 4), 256, 0, stream>>>(dt, xc, xdbl, xz, hend, yg,
                                                    AlF, AlB, DF, DB);

    // out_proj + residual: [8192,1024] x [512,1024]^T -> d_out[row][dir*512+col]
    gemm_k<128, 128, 4, 4, 3><<<dim3(4, 64, 2), 256, 0, stream>>>(
        yg, (long)MROWS * 1024, 1024, wop, wop + 512 * 1024, 1024,
        d_out, 512, 1024, nullptr, 0, x, nullptr, 1024);
}

// Round 5
// 460.935 us; speedup vs baseline: 7.1657x; 1.1290x over previous
//
#include <hip/hip_runtime.h>
#include <hip/hip_bf16.h>
#include <cstdint>

#define DMODEL 1024
#define DHALF  512
#define DINNER 1024
#define DSTATE 16
#define DTRANK 32
#define LSEQ   4096
#define BBATCH 2
#define MROWS  (BBATCH*LSEQ)   // 8192
#define SCH    128             // scan chunks
#define SCT    32              // steps per chunk (SCH*SCT == LSEQ)

using bf16 = __bf16;
using bf16x8 = __attribute__((ext_vector_type(8))) __bf16;
using f32x4  = __attribute__((ext_vector_type(4))) float;

__device__ __forceinline__ float sigmoidf_(float x) { return 1.f / (1.f + __expf(-x)); }
__device__ __forceinline__ float softplusf_(float x) { return fmaxf(x, 0.f) + log1pf(__expf(-fabsf(x))); }

// async global->LDS, 16B per lane; LDS dest = wave-uniform base + lane*16
__device__ __forceinline__ void glds16(const bf16* g, bf16* l) {
    __builtin_amdgcn_global_load_lds(
        (const __attribute__((address_space(1))) void*)g,
        (__attribute__((address_space(3))) void*)l, 16, 0, 0);
}

// ---------------------------------------------------------------- LayerNorm
__global__ __launch_bounds__(256) void ln_kernel(
    const float* __restrict__ x, const float* __restrict__ w,
    const float* __restrict__ b, bf16* __restrict__ xn)
{
    const int row = blockIdx.x;
    const int tid = threadIdx.x;
    const float4 v = *(const float4*)&x[(size_t)row * DMODEL + tid * 4];
    float s  = v.x + v.y + v.z + v.w;
    float s2 = v.x * v.x + v.y * v.y + v.z * v.z + v.w * v.w;
#pragma unroll
    for (int off = 1; off < 64; off <<= 1) {
        s  += __shfl_xor(s, off);
        s2 += __shfl_xor(s2, off);
    }
    __shared__ float red[8];
    const int wid = tid >> 6;
    if ((tid & 63) == 0) { red[wid] = s; red[4 + wid] = s2; }
    __syncthreads();
    s  = red[0] + red[1] + red[2] + red[3];
    s2 = red[4] + red[5] + red[6] + red[7];
    const float mu   = s * (1.f / DMODEL);
    const float var  = s2 * (1.f / DMODEL) - mu * mu;
    const float rstd = rsqrtf(var + 1e-5f);
    const float4 wv = *(const float4*)&w[tid * 4];
    const float4 bv = *(const float4*)&b[tid * 4];
    union { bf16 o[4]; uint2 u; } pk;
    pk.o[0] = (bf16)((v.x - mu) * rstd * wv.x + bv.x);
    pk.o[1] = (bf16)((v.y - mu) * rstd * wv.y + bv.y);
    pk.o[2] = (bf16)((v.z - mu) * rstd * wv.z + bv.z);
    pk.o[3] = (bf16)((v.w - mu) * rstd * wv.w + bv.w);
    *(uint2*)&xn[(size_t)row * DMODEL + tid * 4] = pk.u;
}

// ------------------------------------------------------- weight fp32->bf16
__global__ __launch_bounds__(256) void cvt_weights_kernel(
    const float* __restrict__ s0, const float* __restrict__ s1,
    const float* __restrict__ s2, const float* __restrict__ s3,
    const float* __restrict__ s4, const float* __restrict__ s5,
    const float* __restrict__ s6, const float* __restrict__ s7,
    bf16* __restrict__ d0, bf16* __restrict__ d1, bf16* __restrict__ d2,
    bf16* __restrict__ d3, bf16* __restrict__ d4, bf16* __restrict__ d5,
    bf16* __restrict__ d6, bf16* __restrict__ d7)
{
    const size_t gid = ((size_t)blockIdx.x * 256 + threadIdx.x) * 4;
    const float* s; bf16* dst; size_t off;
    if      (gid < 1048576) { s = s0; dst = d0; off = gid; }
    else if (gid < 2097152) { s = s1; dst = d1; off = gid - 1048576; }
    else if (gid < 2162688) { s = s2; dst = d2; off = gid - 2097152; }
    else if (gid < 2228224) { s = s3; dst = d3; off = gid - 2162688; }
    else if (gid < 2752512) { s = s4; dst = d4; off = gid - 2228224; }
    else if (gid < 3276800) { s = s5; dst = d5; off = gid - 2752512; }
    else if (gid < 3309568) { s = s6; dst = d6; off = gid - 3276800; }
    else if (gid < 3342336) { s = s7; dst = d7; off = gid - 3309568; }
    else return;
    const float4 v = *(const float4*)&s[off];
    union { bf16 o[4]; uint2 u; } pk;
    pk.o[0] = (bf16)v.x; pk.o[1] = (bf16)v.y; pk.o[2] = (bf16)v.z; pk.o[3] = (bf16)v.w;
    *(uint2*)&dst[off] = pk.u;
}

// ----------------------------------------------------------------- GEMM
// C[m,n] = sum_k A[m,k] * W[n,k]. m97 structure: global_load_lds(16B) into
// LINEAR LDS [rows][32], 2 barriers per K-step.
// EPI 0: bf16 store   1: f32+bf16 dual   2: softplus(v+bias[col]) f32
// EPI 3: v + residual f32
template<int BM, int BN, int WTM, int WTN, int EPI>
__global__ __launch_bounds__(256) void gemm_k(
    const bf16* __restrict__ A0, long aDirStride, int lda,
    const bf16* __restrict__ W0, const bf16* __restrict__ W1, int ldw,
    void* __restrict__ C0, long cDirStride, int ldc,
    void* __restrict__ C1, long c1DirStride,
    const float* __restrict__ X0, const float* __restrict__ X1,
    int K)
{
    constexpr int WGN = BN / (WTN * 16);
    static_assert((BM * 32) % 2048 == 0 && (BN * 32) % 2048 == 0, "tile");
    __shared__ alignas(16) bf16 As[BM * 32];
    __shared__ alignas(16) bf16 Bs[BN * 32];
    const int tid = threadIdx.x;
    const int wid = tid >> 6, lane = tid & 63;
    const int wr = wid / WGN, wc = wid % WGN;
    const int bx = blockIdx.x, by = blockIdx.y, bz = blockIdx.z;
    const bf16* A = A0 + (long)bz * aDirStride + (long)by * BM * lda;
    const bf16* W = (bz ? W1 : W0) + (long)bx * BN * ldw;
    f32x4 acc[WTM][WTN] = {};
    for (int k0 = 0; k0 < K; k0 += 32) {
        constexpr int AP = BM * 32 / 2048;
#pragma unroll
        for (int p = 0; p < AP; ++p) {
            const int idx = (p * 256 + tid) * 8;
            const int r = idx >> 5, c = idx & 31;
            glds16(&A[(long)r * lda + k0 + c], &As[p * 2048 + wid * 512]);
        }
        constexpr int BP = BN * 32 / 2048;
#pragma unroll
        for (int p = 0; p < BP; ++p) {
            const int idx = (p * 256 + tid) * 8;
            const int r = idx >> 5, c = idx & 31;
            glds16(&W[(long)r * ldw + k0 + c], &Bs[p * 2048 + wid * 512]);
        }
        __syncthreads();
        const int rA = lane & 15, kO = (lane >> 4) * 8;
        bf16x8 af[WTM], bw[WTN];
#pragma unroll
        for (int i = 0; i < WTM; ++i)
            af[i] = *(const bf16x8*)&As[(wr * WTM * 16 + i * 16 + rA) * 32 + kO];
#pragma unroll
        for (int j = 0; j < WTN; ++j)
            bw[j] = *(const bf16x8*)&Bs[(wc * WTN * 16 + j * 16 + rA) * 32 + kO];
#pragma unroll
        for (int i = 0; i < WTM; ++i)
#pragma unroll
            for (int j = 0; j < WTN; ++j)
                acc[i][j] = __builtin_amdgcn_mfma_f32_16x16x32_bf16(af[i], bw[j], acc[i][j], 0, 0, 0);
        __syncthreads();
    }
    const int rl = (lane >> 4) * 4, cl = lane & 15;
    const int rowBase = by * BM + wr * WTM * 16;
    const int colBase = bx * BN + wc * WTN * 16;
#pragma unroll
    for (int i = 0; i < WTM; ++i)
#pragma unroll
        for (int j = 0; j < WTN; ++j) {
#pragma unroll
            for (int r = 0; r < 4; ++r) {
                const int row = rowBase + i * 16 + rl + r;
                const int col = colBase + j * 16 + cl;
                const float v = acc[i][j][r];
                if constexpr (EPI == 0) {
                    ((bf16*)C0 + (long)bz * cDirStride)[(long)row * ldc + col] = (bf16)v;
                } else if constexpr (EPI == 1) {
                    ((float*)C0 + (long)bz * cDirStride)[(long)row * ldc + col] = v;
                    ((bf16*)C1 + (long)bz * c1DirStride)[(long)row * ldc + col] = (bf16)v;
                } else if constexpr (EPI == 2) {
                    const float* bias = bz ? X1 : X0;
                    ((float*)C0 + (long)bz * cDirStride)[(long)row * ldc + col] =
                        softplusf_(v + bias[col]);
                } else {
                    const long idx = (long)row * ldc + col;
                    ((float*)C0 + (long)bz * cDirStride)[idx] = v + (X0 + (long)bz * cDirStride)[idx];
                }
            }
        }
}

// --------------------------------------------------- depthwise conv4 + SiLU
// thread = 8 consecutive channels of one (dir, m) row
__global__ __launch_bounds__(256) void conv_silu_kernel(
    const bf16* __restrict__ xz, bf16* __restrict__ xc,
    const float* __restrict__ cwF, const float* __restrict__ cbF,
    const float* __restrict__ cwB, const float* __restrict__ cbB)
{
    const size_t gid = (size_t)blockIdx.x * 256 + threadIdx.x; // 2^21
    const int g = (int)(gid & 127);
    const size_t m = (gid >> 7) & (MROWS - 1);
    const int dir = (int)(gid >> 20);
    const int t = (int)(m & (LSEQ - 1));
    const int d0 = g * 8;
    const float* cw = dir ? cwB : cwF;
    const float* cb = dir ? cbB : cbF;
    float acc[8];
#pragma unroll
    for (int e = 0; e < 8; e += 4) *(float4*)&acc[e] = *(const float4*)&cb[d0 + e];
    float4 wv[8];
#pragma unroll
    for (int e = 0; e < 8; ++e) wv[e] = *(const float4*)&cw[(d0 + e) * 4];
    const bf16* src = xz + (size_t)dir * MROWS * 2048 + (m - (size_t)t) * 2048 + d0;
#pragma unroll
    for (int j = 0; j < 4; ++j) {
        const int ts = dir ? (t + 3 - j) : (t - 3 + j);
        if (ts >= 0 && ts < LSEQ) {
            const bf16x8 v = *(const bf16x8*)&src[(size_t)ts * 2048];
            acc[0] = fmaf(j==0?wv[0].x:j==1?wv[0].y:j==2?wv[0].z:wv[0].w, (float)v[0], acc[0]);
            acc[1] = fmaf(j==0?wv[1].x:j==1?wv[1].y:j==2?wv[1].z:wv[1].w, (float)v[1], acc[1]);
            acc[2] = fmaf(j==0?wv[2].x:j==1?wv[2].y:j==2?wv[2].z:wv[2].w, (float)v[2], acc[2]);
            acc[3] = fmaf(j==0?wv[3].x:j==1?wv[3].y:j==2?wv[3].z:wv[3].w, (float)v[3], acc[3]);
            acc[4] = fmaf(j==0?wv[4].x:j==1?wv[4].y:j==2?wv[4].z:wv[4].w, (float)v[4], acc[4]);
            acc[5] = fmaf(j==0?wv[5].x:j==1?wv[5].y:j==2?wv[5].z:wv[5].w, (float)v[5], acc[5]);
            acc[6] = fmaf(j==0?wv[6].x:j==1?wv[6].y:j==2?wv[6].z:wv[6].w, (float)v[6], acc[6]);
            acc[7] = fmaf(j==0?wv[7].x:j==1?wv[7].y:j==2?wv[7].z:wv[7].w, (float)v[7], acc[7]);
        }
    }
    bf16x8 o;
#pragma unroll
    for (int e = 0; e < 8; ++e) { const float s = acc[e] * sigmoidf_(acc[e]); o[e] = (bf16)s; }
    *(bf16x8*)&xc[(size_t)dir * MROWS * DINNER + m * DINNER + d0] = o;
}

// ------------------------------------------------- chunked selective scan
// lane = one channel d; 16 states in registers. Fast path exploits
// a[n] == -(n+1) (A_log = log(arange)): dA[n] = q^(n+1), q = exp(-dt).
// Guarded by a runtime check; general path kept as fallback.
__global__ __launch_bounds__(256) void scan_part1(
    const float* __restrict__ dt, const bf16* __restrict__ xc,
    const float* __restrict__ xdbl,
    float* __restrict__ hend, float* __restrict__ sdtOut,
    const float* __restrict__ AlogF, const float* __restrict__ AlogB)
{
    const int d = blockIdx.x * 256 + threadIdx.x;
    const int chunk = blockIdx.y;
    const int sb = blockIdx.z;
    const int dir = sb >> 1, b = sb & 1;
    const float* Alog = dir ? AlogB : AlogF;
    float a[16];
#pragma unroll
    for (int n = 0; n < 16; n += 4)
        *(float4*)&a[n] = *(const float4*)&Alog[d * 16 + n];
#pragma unroll
    for (int n = 0; n < 16; ++n) a[n] = -__expf(a[n]);
    bool fast = true;
#pragma unroll
    for (int n = 0; n < 16; ++n) fast = fast && (fabsf(a[n] + (float)(n + 1)) <= 1e-3f * (n + 1));
    const size_t base1 = (size_t)dir * MROWS * DINNER + (size_t)b * LSEQ * DINNER;
    const size_t base64 = (size_t)dir * MROWS * 64 + (size_t)b * LSEQ * 64;
    const int t0 = dir ? (LSEQ - 1) : 0;
    const int stp = dir ? -1 : 1;
    const int ts = t0 + stp * (chunk * SCT);
    const float* pdt = dt + base1 + (size_t)ts * DINNER + d;
    const bf16* pxc = xc + base1 + (size_t)ts * DINNER + d;
    const float* pB = xdbl + base64 + (size_t)ts * 64 + 32;
    const long s1 = (long)stp * DINNER, s64 = (long)stp * 64;
    float h[16] = {};
    float sacc = 0.f;
    if (fast) {
#pragma unroll 4
        for (int i = 0; i < SCT; ++i) {
            const float dtv = *pdt;
            const float u = (float)*pxc;
            const float dtu = dtv * u;
            sacc += dtv;
            float B[16];
#pragma unroll
            for (int n = 0; n < 16; n += 4) *(float4*)&B[n] = *(const float4*)&pB[n];
            const float q = __expf(-dtv);
            float p = 1.f;
#pragma unroll
            for (int n = 0; n < 16; ++n) { p *= q; h[n] = fmaf(h[n], p, dtu * B[n]); }
            pdt += s1; pxc += s1; pB += s64;
        }
    } else {
#pragma unroll 4
        for (int i = 0; i < SCT; ++i) {
            const float dtv = *pdt;
            const float u = (float)*pxc;
            const float dtu = dtv * u;
            sacc += dtv;
            float B[16];
#pragma unroll
            for (int n = 0; n < 16; n += 4) *(float4*)&B[n] = *(const float4*)&pB[n];
#pragma unroll
            for (int n = 0; n < 16; ++n) {
                const float dA = __expf(dtv * a[n]);
                h[n] = fmaf(h[n], dA, dtu * B[n]);
            }
            pdt += s1; pxc += s1; pB += s64;
        }
    }
    const size_t o = ((size_t)sb * SCH + chunk) * 16384 + (size_t)d * 16;
#pragma unroll
    for (int n = 0; n < 16; n += 4) *(float4*)&hend[o + n] = *(const float4*)&h[n];
    sdtOut[((size_t)sb * SCH + chunk) * 1024 + d] = sacc;
}

// combine chunk summaries across chunks; hend[c] becomes h_in for chunk c.
// prod(dA) over chunk c = exp(a_n * sdt[c]) (exact: exps share base).
__global__ __launch_bounds__(256) void scan_part2(
    float* __restrict__ hend, const float* __restrict__ sdt,
    const float* __restrict__ AlogF, const float* __restrict__ AlogB)
{
    const size_t gid = (size_t)blockIdx.x * 256 + threadIdx.x;  // 65536
    const int sb = (int)(gid >> 14);
    const int dn = (int)(gid & 16383);
    const int d = dn >> 4;
    const float* Alog = (sb >> 1) ? AlogB : AlogF;
    const float a_n = -__expf(Alog[dn]);
    float h = 0.f;
    size_t idx = (size_t)sb * SCH * 16384 + dn;
    size_t sidx = (size_t)sb * SCH * 1024 + d;
#pragma unroll 4
    for (int c = 0; c < SCH; ++c) {
        const float sd = sdt[sidx];
        const float pe = __expf(a_n * sd);
        const float he = hend[idx];
        hend[idx] = h;
        h = fmaf(pe, h, he);
        idx += 16384; sidx += 1024;
    }
}

// final pass: chunk scan from h_in; y = sum_n h*C; gate with silu(z)
__global__ __launch_bounds__(256) void scan_part3(
    const float* __restrict__ dt, const bf16* __restrict__ xc,
    const float* __restrict__ xdbl, const bf16* __restrict__ xz,
    const float* __restrict__ hin, bf16* __restrict__ yg,
    const float* __restrict__ AlogF, const float* __restrict__ AlogB,
    const float* __restrict__ DF, const float* __restrict__ DB)
{
    const int d = blockIdx.x * 256 + threadIdx.x;
    const int chunk = blockIdx.y;
    const int sb = blockIdx.z;
    const int dir = sb >> 1, b = sb & 1;
    const float* Alog = dir ? AlogB : AlogF;
    const float* Dw = dir ? DB : DF;
    float a[16];
#pragma unroll
    for (int n = 0; n < 16; n += 4)
        *(float4*)&a[n] = *(const float4*)&Alog[d * 16 + n];
#pragma unroll
    for (int n = 0; n < 16; ++n) a[n] = -__expf(a[n]);
    bool fast = true;
#pragma unroll
    for (int n = 0; n < 16; ++n) fast = fast && (fabsf(a[n] + (float)(n + 1)) <= 1e-3f * (n + 1));
    const float Dv = Dw[d];
    const size_t base1 = (size_t)dir * MROWS * DINNER + (size_t)b * LSEQ * DINNER;
    const size_t base64 = (size_t)dir * MROWS * 64 + (size_t)b * LSEQ * 64;
    const size_t baseZ = (size_t)dir * MROWS * 2048 + (size_t)b * LSEQ * 2048;
    const int t0 = dir ? (LSEQ - 1) : 0;
    const int stp = dir ? -1 : 1;
    const int ts = t0 + stp * (chunk * SCT);
    const float* pdt = dt + base1 + (size_t)ts * DINNER + d;
    const bf16* pxc = xc + base1 + (size_t)ts * DINNER + d;
    const float* pB = xdbl + base64 + (size_t)ts * 64 + 32;
    const bf16* pz = xz + baseZ + (size_t)ts * 2048 + 1024 + d;
    bf16* pyg = yg + base1 + (size_t)ts * DINNER + d;
    const long s1 = (long)stp * DINNER, s64 = (long)stp * 64, sZ = (long)stp * 2048;
    float h[16];
    const size_t o = ((size_t)sb * SCH + chunk) * 16384 + (size_t)d * 16;
#pragma unroll
    for (int n = 0; n < 16; n += 4) *(float4*)&h[n] = *(const float4*)&hin[o + n];
    if (fast) {
#pragma unroll 4
        for (int i = 0; i < SCT; ++i) {
            const float dtv = *pdt;
            const float u = (float)*pxc;
            const float dtu = dtv * u;
            float B[16], C[16];
#pragma unroll
            for (int n = 0; n < 16; n += 4) *(float4*)&B[n] = *(const float4*)&pB[n];
#pragma unroll
            for (int n = 0; n < 16; n += 4) *(float4*)&C[n] = *(const float4*)&pB[16 + n];
            const float q = __expf(-dtv);
            float p = 1.f;
            float y0 = 0.f, y1 = 0.f, y2 = 0.f, y3 = 0.f;
#pragma unroll
            for (int n = 0; n < 16; n += 4) {
                p *= q; h[n]     = fmaf(h[n],     p, dtu * B[n]);     y0 = fmaf(h[n],     C[n],     y0);
                p *= q; h[n + 1] = fmaf(h[n + 1], p, dtu * B[n + 1]); y1 = fmaf(h[n + 1], C[n + 1], y1);
                p *= q; h[n + 2] = fmaf(h[n + 2], p, dtu * B[n + 2]); y2 = fmaf(h[n + 2], C[n + 2], y2);
                p *= q; h[n + 3] = fmaf(h[n + 3], p, dtu * B[n + 3]); y3 = fmaf(h[n + 3], C[n + 3], y3);
            }
            const float y = (y0 + y1) + (y2 + y3);
            const float z = (float)*pz;
            const float out = (y + Dv * u) * (z * sigmoidf_(z));
            *pyg = (bf16)out;
            pdt += s1; pxc += s1; pB += s64; pz += sZ; pyg += s1;
        }
    } else {
#pragma unroll 4
        for (int i = 0; i < SCT; ++i) {
            const float dtv = *pdt;
            const float u = (float)*pxc;
            const float dtu = dtv * u;
            float B[16], C[16];
#pragma unroll
            for (int n = 0; n < 16; n += 4) *(float4*)&B[n] = *(const float4*)&pB[n];
#pragma unroll
            for (int n = 0; n < 16; n += 4) *(float4*)&C[n] = *(const float4*)&pB[16 + n];
            float y0 = 0.f, y1 = 0.f, y2 = 0.f, y3 = 0.f;
#pragma unroll
            for (int n = 0; n < 16; n += 4) {
                float dA;
                dA = __expf(dtv * a[n]);     h[n]     = fmaf(h[n],     dA, dtu * B[n]);     y0 = fmaf(h[n],     C[n],     y0);
                dA = __expf(dtv * a[n + 1]); h[n + 1] = fmaf(h[n + 1], dA, dtu * B[n + 1]); y1 = fmaf(h[n + 1], C[n + 1], y1);
                dA = __expf(dtv * a[n + 2]); h[n + 2] = fmaf(h[n + 2], dA, dtu * B[n + 2]); y2 = fmaf(h[n + 2], C[n + 2], y2);
                dA = __expf(dtv * a[n + 3]); h[n + 3] = fmaf(h[n + 3], dA, dtu * B[n + 3]); y3 = fmaf(h[n + 3], C[n + 3], y3);
            }
            const float y = (y0 + y1) + (y2 + y3);
            const float z = (float)*pz;
            const float out = (y + Dv * u) * (z * sigmoidf_(z));
            *pyg = (bf16)out;
            pdt += s1; pxc += s1; pB += s64; pz += sZ; pyg += s1;
        }
    }
}

// ------------------------------------------------------------------- launch
extern "C" void kernel_launch(void* const* d_in, const int* in_sizes, int n_in,
                              void* d_out, int out_size, void* d_ws, size_t ws_size,
                              hipStream_t stream)
{
    const float* x      = (const float*)d_in[0];
    const float* norm_w = (const float*)d_in[1];
    const float* norm_b = (const float*)d_in[2];
    const float* ipF  = (const float*)d_in[3];
    const float* cwF  = (const float*)d_in[4];
    const float* cbF  = (const float*)d_in[5];
    const float* xpF  = (const float*)d_in[6];
    const float* dtwF = (const float*)d_in[7];
    const float* dtbF = (const float*)d_in[8];
    const float* AlF  = (const float*)d_in[9];
    const float* DF   = (const float*)d_in[10];
    const float* opF  = (const float*)d_in[11];
    const float* ipB  = (const float*)d_in[12];
    const float* cwB  = (const float*)d_in[13];
    const float* cbB  = (const float*)d_in[14];
    const float* xpB  = (const float*)d_in[15];
    const float* dtwB = (const float*)d_in[16];
    const float* dtbB = (const float*)d_in[17];
    const float* AlB  = (const float*)d_in[18];
    const float* DB   = (const float*)d_in[19];
    const float* opB  = (const float*)d_in[20];

    char* ws = (char*)d_ws;
    size_t off = 0;
    auto alloc = [&](size_t bytes) -> void* {
        void* p = ws + off;
        off += (bytes + 255) & ~(size_t)255;
        return p;
    };
    bf16*  xn      = (bf16*)alloc((size_t)MROWS * DMODEL * 2);
    bf16*  win     = (bf16*)alloc((size_t)2 * 2048 * 512 * 2);
    bf16*  wxp     = (bf16*)alloc((size_t)2 * 64 * 1024 * 2);
    bf16*  wop     = (bf16*)alloc((size_t)2 * 512 * 1024 * 2);
    bf16*  wdt     = (bf16*)alloc((size_t)2 * 1024 * 32 * 2);
    bf16*  xz      = (bf16*)alloc((size_t)2 * MROWS * 2048 * 2);
    bf16*  xc      = (bf16*)alloc((size_t)2 * MROWS * 1024 * 2);
    float* xdbl    = (float*)alloc((size_t)2 * MROWS * 64 * 4);
    bf16*  xdbl_bf = (bf16*)alloc((size_t)2 * MROWS * 64 * 2);
    float* dt      = (float*)alloc((size_t)2 * MROWS * 1024 * 4);
    bf16*  yg      = (bf16*)alloc((size_t)2 * MROWS * 1024 * 2);
    float* hend    = (float*)alloc((size_t)4 * SCH * 16384 * 4);
    float* sdt     = (float*)alloc((size_t)4 * SCH * 1024 * 4);

    cvt_weights_kernel<<<3264, 256, 0, stream>>>(
        ipF, ipB, xpF, xpB, opF, opB, dtwF, dtwB,
        win, win + 2048 * 512, wxp, wxp + 64 * 1024,
        wop, wop + 512 * 1024, wdt, wdt + 1024 * 32);

    ln_kernel<<<MROWS, 256, 0, stream>>>(x, norm_w, norm_b, xn);

    // in_proj: [8192,512] x [2048,512]^T -> xz bf16 [dir][8192][2048]
    gemm_k<128, 128, 4, 4, 0><<<dim3(16, 64, 2), 256, 0, stream>>>(
        xn, 512, DMODEL, win, win + 2048 * 512, 512,
        xz, (long)MROWS * 2048, 2048, nullptr, 0, nullptr, nullptr, 512);

    conv_silu_kernel<<<8192, 256, 0, stream>>>(xz, xc, cwF, cbF, cwB, cbB);

    // x_proj: [8192,1024] x [64,1024]^T -> x_dbl f32 + bf16 shadow
    gemm_k<64, 64, 2, 2, 1><<<dim3(1, 128, 2), 256, 0, stream>>>(
        xc, (long)MROWS * 1024, 1024, wxp, wxp + 64 * 1024, 1024,
        xdbl, (long)MROWS * 64, 64, xdbl_bf, (long)MROWS * 64, nullptr, nullptr, 1024);

    // dt_proj: [8192,32] x [1024,32]^T -> softplus(+bias) f32
    gemm_k<128, 128, 4, 4, 2><<<dim3(8, 64, 2), 256, 0, stream>>>(
        xdbl_bf, (long)MROWS * 64, 64, wdt, wdt + 1024 * 32, 32,
        dt, (long)MROWS * 1024, 1024, nullptr, 0, dtbF, dtbB, 32);

    // chunked scan: 128 chunks x 32 steps, lane = channel
    scan_part1<<<dim3(4, SCH, 4), 256, 0, stream>>>(dt, xc, xdbl, hend, sdt, AlF, AlB);
    scan_part2<<<256, 256, 0, stream>>>(hend, sdt, AlF, AlB);
    scan_part3<<<dim3(4, SCH, 4), 256, 0, stream>>>(dt, xc, xdbl, xz, hend, yg,
                                                    AlF, AlB, DF, DB);

    // out_proj + residual: [8192,1024] x [512,1024]^T -> d_out[row][dir*512+col]
    gemm_k<128, 128, 4, 4, 3><<<dim3(4, 64, 2), 256, 0, stream>>>(
        yg, (long)MROWS * 1024, 1024, wop, wop + 512 * 1024, 1024,
        d_out, 512, 1024, nullptr, 0, x, nullptr, 1024);
}

// Round 6
// 419.225 us; speedup vs baseline: 7.8787x; 1.0995x over previous
//
#include <hip/hip_runtime.h>
#include <hip/hip_bf16.h>
#include <cstdint>

#define DMODEL 1024
#define DHALF  512
#define DINNER 1024
#define DSTATE 16
#define DTRANK 32
#define LSEQ   4096
#define BBATCH 2
#define MROWS  (BBATCH*LSEQ)   // 8192
#define SCH    128             // scan chunks
#define SCT    32              // steps per chunk (SCH*SCT == LSEQ)

using bf16 = __bf16;
using bf16x8 = __attribute__((ext_vector_type(8))) __bf16;
using f32x4  = __attribute__((ext_vector_type(4))) float;

__device__ __forceinline__ float sigmoidf_(float x) { return 1.f / (1.f + __expf(-x)); }
__device__ __forceinline__ float softplusf_(float x) { return fmaxf(x, 0.f) + log1pf(__expf(-fabsf(x))); }

// async global->LDS, 16B per lane; LDS dest = wave-uniform base + lane*16
__device__ __forceinline__ void glds16(const bf16* g, bf16* l) {
    __builtin_amdgcn_global_load_lds(
        (const __attribute__((address_space(1))) void*)g,
        (__attribute__((address_space(3))) void*)l, 16, 0, 0);
}

// ---------------------------------------------------------------- LayerNorm
__global__ __launch_bounds__(256) void ln_kernel(
    const float* __restrict__ x, const float* __restrict__ w,
    const float* __restrict__ b, bf16* __restrict__ xn)
{
    const int row = blockIdx.x;
    const int tid = threadIdx.x;
    const float4 v = *(const float4*)&x[(size_t)row * DMODEL + tid * 4];
    float s  = v.x + v.y + v.z + v.w;
    float s2 = v.x * v.x + v.y * v.y + v.z * v.z + v.w * v.w;
#pragma unroll
    for (int off = 1; off < 64; off <<= 1) {
        s  += __shfl_xor(s, off);
        s2 += __shfl_xor(s2, off);
    }
    __shared__ float red[8];
    const int wid = tid >> 6;
    if ((tid & 63) == 0) { red[wid] = s; red[4 + wid] = s2; }
    __syncthreads();
    s  = red[0] + red[1] + red[2] + red[3];
    s2 = red[4] + red[5] + red[6] + red[7];
    const float mu   = s * (1.f / DMODEL);
    const float var  = s2 * (1.f / DMODEL) - mu * mu;
    const float rstd = rsqrtf(var + 1e-5f);
    const float4 wv = *(const float4*)&w[tid * 4];
    const float4 bv = *(const float4*)&b[tid * 4];
    union { bf16 o[4]; uint2 u; } pk;
    pk.o[0] = (bf16)((v.x - mu) * rstd * wv.x + bv.x);
    pk.o[1] = (bf16)((v.y - mu) * rstd * wv.y + bv.y);
    pk.o[2] = (bf16)((v.z - mu) * rstd * wv.z + bv.z);
    pk.o[3] = (bf16)((v.w - mu) * rstd * wv.w + bv.w);
    *(uint2*)&xn[(size_t)row * DMODEL + tid * 4] = pk.u;
}

// ------------------------------------------------------- weight fp32->bf16
__global__ __launch_bounds__(256) void cvt_weights_kernel(
    const float* __restrict__ s0, const float* __restrict__ s1,
    const float* __restrict__ s2, const float* __restrict__ s3,
    const float* __restrict__ s4, const float* __restrict__ s5,
    const float* __restrict__ s6, const float* __restrict__ s7,
    bf16* __restrict__ d0, bf16* __restrict__ d1, bf16* __restrict__ d2,
    bf16* __restrict__ d3, bf16* __restrict__ d4, bf16* __restrict__ d5,
    bf16* __restrict__ d6, bf16* __restrict__ d7)
{
    const size_t gid = ((size_t)blockIdx.x * 256 + threadIdx.x) * 4;
    const float* s; bf16* dst; size_t off;
    if      (gid < 1048576) { s = s0; dst = d0; off = gid; }
    else if (gid < 2097152) { s = s1; dst = d1; off = gid - 1048576; }
    else if (gid < 2162688) { s = s2; dst = d2; off = gid - 2097152; }
    else if (gid < 2228224) { s = s3; dst = d3; off = gid - 2162688; }
    else if (gid < 2752512) { s = s4; dst = d4; off = gid - 2228224; }
    else if (gid < 3276800) { s = s5; dst = d5; off = gid - 2752512; }
    else if (gid < 3309568) { s = s6; dst = d6; off = gid - 3276800; }
    else if (gid < 3342336) { s = s7; dst = d7; off = gid - 3309568; }
    else return;
    const float4 v = *(const float4*)&s[off];
    union { bf16 o[4]; uint2 u; } pk;
    pk.o[0] = (bf16)v.x; pk.o[1] = (bf16)v.y; pk.o[2] = (bf16)v.z; pk.o[3] = (bf16)v.w;
    *(uint2*)&dst[off] = pk.u;
}

// ----------------------------------------------------------------- GEMM
// C[m,n] = sum_k A[m,k] * W[n,k]. m97 structure: global_load_lds(16B) into
// LINEAR LDS [rows][32], 2 barriers per K-step.
// EPI 0: bf16 store   1: f32+bf16 dual   2: softplus(v+bias[col]) f32
// EPI 3: v + residual f32
template<int BM, int BN, int WTM, int WTN, int EPI>
__global__ __launch_bounds__(256) void gemm_k(
    const bf16* __restrict__ A0, long aDirStride, int lda,
    const bf16* __restrict__ W0, const bf16* __restrict__ W1, int ldw,
    void* __restrict__ C0, long cDirStride, int ldc,
    void* __restrict__ C1, long c1DirStride,
    const float* __restrict__ X0, const float* __restrict__ X1,
    int K)
{
    constexpr int WGN = BN / (WTN * 16);
    static_assert((BM * 32) % 2048 == 0 && (BN * 32) % 2048 == 0, "tile");
    __shared__ alignas(16) bf16 As[BM * 32];
    __shared__ alignas(16) bf16 Bs[BN * 32];
    const int tid = threadIdx.x;
    const int wid = tid >> 6, lane = tid & 63;
    const int wr = wid / WGN, wc = wid % WGN;
    const int bx = blockIdx.x, by = blockIdx.y, bz = blockIdx.z;
    const bf16* A = A0 + (long)bz * aDirStride + (long)by * BM * lda;
    const bf16* W = (bz ? W1 : W0) + (long)bx * BN * ldw;
    f32x4 acc[WTM][WTN] = {};
    for (int k0 = 0; k0 < K; k0 += 32) {
        constexpr int AP = BM * 32 / 2048;
#pragma unroll
        for (int p = 0; p < AP; ++p) {
            const int idx = (p * 256 + tid) * 8;
            const int r = idx >> 5, c = idx & 31;
            glds16(&A[(long)r * lda + k0 + c], &As[p * 2048 + wid * 512]);
        }
        constexpr int BP = BN * 32 / 2048;
#pragma unroll
        for (int p = 0; p < BP; ++p) {
            const int idx = (p * 256 + tid) * 8;
            const int r = idx >> 5, c = idx & 31;
            glds16(&W[(long)r * ldw + k0 + c], &Bs[p * 2048 + wid * 512]);
        }
        __syncthreads();
        const int rA = lane & 15, kO = (lane >> 4) * 8;
        bf16x8 af[WTM], bw[WTN];
#pragma unroll
        for (int i = 0; i < WTM; ++i)
            af[i] = *(const bf16x8*)&As[(wr * WTM * 16 + i * 16 + rA) * 32 + kO];
#pragma unroll
        for (int j = 0; j < WTN; ++j)
            bw[j] = *(const bf16x8*)&Bs[(wc * WTN * 16 + j * 16 + rA) * 32 + kO];
#pragma unroll
        for (int i = 0; i < WTM; ++i)
#pragma unroll
            for (int j = 0; j < WTN; ++j)
                acc[i][j] = __builtin_amdgcn_mfma_f32_16x16x32_bf16(af[i], bw[j], acc[i][j], 0, 0, 0);
        __syncthreads();
    }
    const int rl = (lane >> 4) * 4, cl = lane & 15;
    const int rowBase = by * BM + wr * WTM * 16;
    const int colBase = bx * BN + wc * WTN * 16;
#pragma unroll
    for (int i = 0; i < WTM; ++i)
#pragma unroll
        for (int j = 0; j < WTN; ++j) {
#pragma unroll
            for (int r = 0; r < 4; ++r) {
                const int row = rowBase + i * 16 + rl + r;
                const int col = colBase + j * 16 + cl;
                const float v = acc[i][j][r];
                if constexpr (EPI == 0) {
                    ((bf16*)C0 + (long)bz * cDirStride)[(long)row * ldc + col] = (bf16)v;
                } else if constexpr (EPI == 1) {
                    ((float*)C0 + (long)bz * cDirStride)[(long)row * ldc + col] = v;
                    ((bf16*)C1 + (long)bz * c1DirStride)[(long)row * ldc + col] = (bf16)v;
                } else if constexpr (EPI == 2) {
                    const float* bias = bz ? X1 : X0;
                    ((float*)C0 + (long)bz * cDirStride)[(long)row * ldc + col] =
                        softplusf_(v + bias[col]);
                } else {
                    const long idx = (long)row * ldc + col;
                    ((float*)C0 + (long)bz * cDirStride)[idx] = v + (X0 + (long)bz * cDirStride)[idx];
                }
            }
        }
}

// --------------------------------------------------- depthwise conv4 + SiLU
// thread = 8 channels x 8 timesteps. Weights loaded once, rolling 4-row
// window of x in registers -> ~0.45 VMEM instr per output (was ~1.9).
#define CT 8
__global__ __launch_bounds__(256) void conv_silu_kernel(
    const bf16* __restrict__ xz, bf16* __restrict__ xc,
    const float* __restrict__ cwF, const float* __restrict__ cbF,
    const float* __restrict__ cwB, const float* __restrict__ cbB)
{
    const size_t gid = (size_t)blockIdx.x * 256 + threadIdx.x; // 2^18
    const int g = (int)(gid & 127);            // channel group (8 ch)
    const int tt = (int)((gid >> 7) & (LSEQ / CT - 1));
    const int b = (int)((gid >> 16) & 1);
    const int dir = (int)(gid >> 17);          // wave-uniform
    const int d0 = g * 8;
    const float* cw = dir ? cwB : cwF;
    const float* cb = dir ? cbB : cbF;
    float bias[8];
#pragma unroll
    for (int e = 0; e < 8; e += 4) *(float4*)&bias[e] = *(const float4*)&cb[d0 + e];
    float4 wv[8];
#pragma unroll
    for (int e = 0; e < 8; ++e) wv[e] = *(const float4*)&cw[(d0 + e) * 4];
    const int t0 = tt * CT;
    const size_t rowBase = (size_t)dir * MROWS * 2048 + (size_t)b * LSEQ * 2048;
    const bf16* src = xz + rowBase + d0;
    bf16* dst = xc + (size_t)dir * MROWS * DINNER + (size_t)b * LSEQ * DINNER
                + (size_t)t0 * DINNER + d0;

    // window rows: fwd out[t] needs x[t-3..t]; bwd out[t] needs x[t..t+3].
    float w0[8] = {}, w1[8] = {}, w2[8] = {};   // the 3 "older" rows
    auto loadRow = [&](int ts, float* r) {
        if (ts >= 0 && ts < LSEQ) {
            const bf16x8 v = *(const bf16x8*)&src[(size_t)ts * 2048];
#pragma unroll
            for (int e = 0; e < 8; ++e) r[e] = (float)v[e];
        } else {
#pragma unroll
            for (int e = 0; e < 8; ++e) r[e] = 0.f;
        }
    };
    if (!dir) { loadRow(t0 - 3, w0); loadRow(t0 - 2, w1); loadRow(t0 - 1, w2); }
    else      { loadRow(t0,     w0); loadRow(t0 + 1, w1); loadRow(t0 + 2, w2); }

#pragma unroll
    for (int i = 0; i < CT; ++i) {
        float w3[8];
        loadRow(dir ? (t0 + i + 3) : (t0 + i), w3);
        bf16x8 o;
        if (!dir) {
            // out = b + wx.x*w0 + wx.y*w1 + wx.z*w2 + wx.w*w3
#pragma unroll
            for (int e = 0; e < 8; ++e) {
                float acc = bias[e];
                acc = fmaf(wv[e].x, w0[e], acc);
                acc = fmaf(wv[e].y, w1[e], acc);
                acc = fmaf(wv[e].z, w2[e], acc);
                acc = fmaf(wv[e].w, w3[e], acc);
                const float s = acc * sigmoidf_(acc);
                o[e] = (bf16)s;
            }
        } else {
            // out[t] = b + wx.w*x[t] + wx.z*x[t+1] + wx.y*x[t+2] + wx.x*x[t+3]
#pragma unroll
            for (int e = 0; e < 8; ++e) {
                float acc = bias[e];
                acc = fmaf(wv[e].w, w0[e], acc);
                acc = fmaf(wv[e].z, w1[e], acc);
                acc = fmaf(wv[e].y, w2[e], acc);
                acc = fmaf(wv[e].x, w3[e], acc);
                const float s = acc * sigmoidf_(acc);
                o[e] = (bf16)s;
            }
        }
        *(bf16x8*)&dst[(size_t)i * DINNER] = o;
        // shift window
#pragma unroll
        for (int e = 0; e < 8; ++e) { w0[e] = w1[e]; w1[e] = w2[e]; w2[e] = w3[e]; }
    }
}

// ------------------------------------------------- chunked selective scan
// lane = one channel d; 16 states in registers. Fast path exploits
// a[n] == -(n+1) (A_log = log(arange)): dA[n] = q^(n+1), q = exp(-dt).
// Guarded by a runtime check; general path kept as fallback.
__global__ __launch_bounds__(256) void scan_part1(
    const float* __restrict__ dt, const bf16* __restrict__ xc,
    const float* __restrict__ xdbl,
    float* __restrict__ hend, float* __restrict__ sdtOut,
    const float* __restrict__ AlogF, const float* __restrict__ AlogB)
{
    const int d = blockIdx.x * 256 + threadIdx.x;
    const int chunk = blockIdx.y;
    const int sb = blockIdx.z;
    const int dir = sb >> 1, b = sb & 1;
    const float* Alog = dir ? AlogB : AlogF;
    float a[16];
#pragma unroll
    for (int n = 0; n < 16; n += 4)
        *(float4*)&a[n] = *(const float4*)&Alog[d * 16 + n];
#pragma unroll
    for (int n = 0; n < 16; ++n) a[n] = -__expf(a[n]);
    bool fast = true;
#pragma unroll
    for (int n = 0; n < 16; ++n) fast = fast && (fabsf(a[n] + (float)(n + 1)) <= 1e-3f * (n + 1));
    const size_t base1 = (size_t)dir * MROWS * DINNER + (size_t)b * LSEQ * DINNER;
    const size_t base64 = (size_t)dir * MROWS * 64 + (size_t)b * LSEQ * 64;
    const int t0 = dir ? (LSEQ - 1) : 0;
    const int stp = dir ? -1 : 1;
    const int ts = t0 + stp * (chunk * SCT);
    const float* pdt = dt + base1 + (size_t)ts * DINNER + d;
    const bf16* pxc = xc + base1 + (size_t)ts * DINNER + d;
    const float* pB = xdbl + base64 + (size_t)ts * 64 + 32;
    const long s1 = (long)stp * DINNER, s64 = (long)stp * 64;
    float h[16] = {};
    float sacc = 0.f;
    if (fast) {
#pragma unroll 4
        for (int i = 0; i < SCT; ++i) {
            const float dtv = *pdt;
            const float u = (float)*pxc;
            const float dtu = dtv * u;
            sacc += dtv;
            float B[16];
#pragma unroll
            for (int n = 0; n < 16; n += 4) *(float4*)&B[n] = *(const float4*)&pB[n];
            const float q = __expf(-dtv);
            float p = 1.f;
#pragma unroll
            for (int n = 0; n < 16; ++n) { p *= q; h[n] = fmaf(h[n], p, dtu * B[n]); }
            pdt += s1; pxc += s1; pB += s64;
        }
    } else {
#pragma unroll 4
        for (int i = 0; i < SCT; ++i) {
            const float dtv = *pdt;
            const float u = (float)*pxc;
            const float dtu = dtv * u;
            sacc += dtv;
            float B[16];
#pragma unroll
            for (int n = 0; n < 16; n += 4) *(float4*)&B[n] = *(const float4*)&pB[n];
#pragma unroll
            for (int n = 0; n < 16; ++n) {
                const float dA = __expf(dtv * a[n]);
                h[n] = fmaf(h[n], dA, dtu * B[n]);
            }
            pdt += s1; pxc += s1; pB += s64;
        }
    }
    const size_t o = ((size_t)sb * SCH + chunk) * 16384 + (size_t)d * 16;
#pragma unroll
    for (int n = 0; n < 16; n += 4) *(float4*)&hend[o + n] = *(const float4*)&h[n];
    sdtOut[((size_t)sb * SCH + chunk) * 1024 + d] = sacc;
}

// combine chunk summaries across chunks; hend[c] becomes h_in for chunk c.
// prod(dA) over chunk c = exp(a_n * sdt[c]) (exact: exps share base).
__global__ __launch_bounds__(256) void scan_part2(
    float* __restrict__ hend, const float* __restrict__ sdt,
    const float* __restrict__ AlogF, const float* __restrict__ AlogB)
{
    const size_t gid = (size_t)blockIdx.x * 256 + threadIdx.x;  // 65536
    const int sb = (int)(gid >> 14);
    const int dn = (int)(gid & 16383);
    const int d = dn >> 4;
    const float* Alog = (sb >> 1) ? AlogB : AlogF;
    const float a_n = -__expf(Alog[dn]);
    float h = 0.f;
    size_t idx = (size_t)sb * SCH * 16384 + dn;
    size_t sidx = (size_t)sb * SCH * 1024 + d;
#pragma unroll 4
    for (int c = 0; c < SCH; ++c) {
        const float sd = sdt[sidx];
        const float pe = __expf(a_n * sd);
        const float he = hend[idx];
        hend[idx] = h;
        h = fmaf(pe, h, he);
        idx += 16384; sidx += 1024;
    }
}

// final pass: chunk scan from h_in; y = sum_n h*C; gate with silu(z)
__global__ __launch_bounds__(256) void scan_part3(
    const float* __restrict__ dt, const bf16* __restrict__ xc,
    const float* __restrict__ xdbl, const bf16* __restrict__ xz,
    const float* __restrict__ hin, bf16* __restrict__ yg,
    const float* __restrict__ AlogF, const float* __restrict__ AlogB,
    const float* __restrict__ DF, const float* __restrict__ DB)
{
    const int d = blockIdx.x * 256 + threadIdx.x;
    const int chunk = blockIdx.y;
    const int sb = blockIdx.z;
    const int dir = sb >> 1, b = sb & 1;
    const float* Alog = dir ? AlogB : AlogF;
    const float* Dw = dir ? DB : DF;
    float a[16];
#pragma unroll
    for (int n = 0; n < 16; n += 4)
        *(float4*)&a[n] = *(const float4*)&Alog[d * 16 + n];
#pragma unroll
    for (int n = 0; n < 16; ++n) a[n] = -__expf(a[n]);
    bool fast = true;
#pragma unroll
    for (int n = 0; n < 16; ++n) fast = fast && (fabsf(a[n] + (float)(n + 1)) <= 1e-3f * (n + 1));
    const float Dv = Dw[d];
    const size_t base1 = (size_t)dir * MROWS * DINNER + (size_t)b * LSEQ * DINNER;
    const size_t base64 = (size_t)dir * MROWS * 64 + (size_t)b * LSEQ * 64;
    const size_t baseZ = (size_t)dir * MROWS * 2048 + (size_t)b * LSEQ * 2048;
    const int t0 = dir ? (LSEQ - 1) : 0;
    const int stp = dir ? -1 : 1;
    const int ts = t0 + stp * (chunk * SCT);
    const float* pdt = dt + base1 + (size_t)ts * DINNER + d;
    const bf16* pxc = xc + base1 + (size_t)ts * DINNER + d;
    const float* pB = xdbl + base64 + (size_t)ts * 64 + 32;
    const bf16* pz = xz + baseZ + (size_t)ts * 2048 + 1024 + d;
    bf16* pyg = yg + base1 + (size_t)ts * DINNER + d;
    const long s1 = (long)stp * DINNER, s64 = (long)stp * 64, sZ = (long)stp * 2048;
    float h[16];
    const size_t o = ((size_t)sb * SCH + chunk) * 16384 + (size_t)d * 16;
#pragma unroll
    for (int n = 0; n < 16; n += 4) *(float4*)&h[n] = *(const float4*)&hin[o + n];
    if (fast) {
#pragma unroll 4
        for (int i = 0; i < SCT; ++i) {
            const float dtv = *pdt;
            const float u = (float)*pxc;
            const float dtu = dtv * u;
            float B[16], C[16];
#pragma unroll
            for (int n = 0; n < 16; n += 4) *(float4*)&B[n] = *(const float4*)&pB[n];
#pragma unroll
            for (int n = 0; n < 16; n += 4) *(float4*)&C[n] = *(const float4*)&pB[16 + n];
            const float q = __expf(-dtv);
            float p = 1.f;
            float y0 = 0.f, y1 = 0.f, y2 = 0.f, y3 = 0.f;
#pragma unroll
            for (int n = 0; n < 16; n += 4) {
                p *= q; h[n]     = fmaf(h[n],     p, dtu * B[n]);     y0 = fmaf(h[n],     C[n],     y0);
                p *= q; h[n + 1] = fmaf(h[n + 1], p, dtu * B[n + 1]); y1 = fmaf(h[n + 1], C[n + 1], y1);
                p *= q; h[n + 2] = fmaf(h[n + 2], p, dtu * B[n + 2]); y2 = fmaf(h[n + 2], C[n + 2], y2);
                p *= q; h[n + 3] = fmaf(h[n + 3], p, dtu * B[n + 3]); y3 = fmaf(h[n + 3], C[n + 3], y3);
            }
            const float y = (y0 + y1) + (y2 + y3);
            const float z = (float)*pz;
            const float out = (y + Dv * u) * (z * sigmoidf_(z));
            *pyg = (bf16)out;
            pdt += s1; pxc += s1; pB += s64; pz += sZ; pyg += s1;
        }
    } else {
#pragma unroll 4
        for (int i = 0; i < SCT; ++i) {
            const float dtv = *pdt;
            const float u = (float)*pxc;
            const float dtu = dtv * u;
            float B[16], C[16];
#pragma unroll
            for (int n = 0; n < 16; n += 4) *(float4*)&B[n] = *(const float4*)&pB[n];
#pragma unroll
            for (int n = 0; n < 16; n += 4) *(float4*)&C[n] = *(const float4*)&pB[16 + n];
            float y0 = 0.f, y1 = 0.f, y2 = 0.f, y3 = 0.f;
#pragma unroll
            for (int n = 0; n < 16; n += 4) {
                float dA;
                dA = __expf(dtv * a[n]);     h[n]     = fmaf(h[n],     dA, dtu * B[n]);     y0 = fmaf(h[n],     C[n],     y0);
                dA = __expf(dtv * a[n + 1]); h[n + 1] = fmaf(h[n + 1], dA, dtu * B[n + 1]); y1 = fmaf(h[n + 1], C[n + 1], y1);
                dA = __expf(dtv * a[n + 2]); h[n + 2] = fmaf(h[n + 2], dA, dtu * B[n + 2]); y2 = fmaf(h[n + 2], C[n + 2], y2);
                dA = __expf(dtv * a[n + 3]); h[n + 3] = fmaf(h[n + 3], dA, dtu * B[n + 3]); y3 = fmaf(h[n + 3], C[n + 3], y3);
            }
            const float y = (y0 + y1) + (y2 + y3);
            const float z = (float)*pz;
            const float out = (y + Dv * u) * (z * sigmoidf_(z));
            *pyg = (bf16)out;
            pdt += s1; pxc += s1; pB += s64; pz += sZ; pyg += s1;
        }
    }
}

// ------------------------------------------------------------------- launch
extern "C" void kernel_launch(void* const* d_in, const int* in_sizes, int n_in,
                              void* d_out, int out_size, void* d_ws, size_t ws_size,
                              hipStream_t stream)
{
    const float* x      = (const float*)d_in[0];
    const float* norm_w = (const float*)d_in[1];
    const float* norm_b = (const float*)d_in[2];
    const float* ipF  = (const float*)d_in[3];
    const float* cwF  = (const float*)d_in[4];
    const float* cbF  = (const float*)d_in[5];
    const float* xpF  = (const float*)d_in[6];
    const float* dtwF = (const float*)d_in[7];
    const float* dtbF = (const float*)d_in[8];
    const float* AlF  = (const float*)d_in[9];
    const float* DF   = (const float*)d_in[10];
    const float* opF  = (const float*)d_in[11];
    const float* ipB  = (const float*)d_in[12];
    const float* cwB  = (const float*)d_in[13];
    const float* cbB  = (const float*)d_in[14];
    const float* xpB  = (const float*)d_in[15];
    const float* dtwB = (const float*)d_in[16];
    const float* dtbB = (const float*)d_in[17];
    const float* AlB  = (const float*)d_in[18];
    const float* DB   = (const float*)d_in[19];
    const float* opB  = (const float*)d_in[20];

    char* ws = (char*)d_ws;
    size_t off = 0;
    auto alloc = [&](size_t bytes) -> void* {
        void* p = ws + off;
        off += (bytes + 255) & ~(size_t)255;
        return p;
    };
    bf16*  xn      = (bf16*)alloc((size_t)MROWS * DMODEL * 2);
    bf16*  win     = (bf16*)alloc((size_t)2 * 2048 * 512 * 2);
    bf16*  wxp     = (bf16*)alloc((size_t)2 * 64 * 1024 * 2);
    bf16*  wop     = (bf16*)alloc((size_t)2 * 512 * 1024 * 2);
    bf16*  wdt     = (bf16*)alloc((size_t)2 * 1024 * 32 * 2);
    bf16*  xz      = (bf16*)alloc((size_t)2 * MROWS * 2048 * 2);
    bf16*  xc      = (bf16*)alloc((size_t)2 * MROWS * 1024 * 2);
    float* xdbl    = (float*)alloc((size_t)2 * MROWS * 64 * 4);
    bf16*  xdbl_bf = (bf16*)alloc((size_t)2 * MROWS * 64 * 2);
    float* dt      = (float*)alloc((size_t)2 * MROWS * 1024 * 4);
    bf16*  yg      = (bf16*)alloc((size_t)2 * MROWS * 1024 * 2);
    float* hend    = (float*)alloc((size_t)4 * SCH * 16384 * 4);
    float* sdt     = (float*)alloc((size_t)4 * SCH * 1024 * 4);

    cvt_weights_kernel<<<3264, 256, 0, stream>>>(
        ipF, ipB, xpF, xpB, opF, opB, dtwF, dtwB,
        win, win + 2048 * 512, wxp, wxp + 64 * 1024,
        wop, wop + 512 * 1024, wdt, wdt + 1024 * 32);

    ln_kernel<<<MROWS, 256, 0, stream>>>(x, norm_w, norm_b, xn);

    // in_proj: [8192,512] x [2048,512]^T -> xz bf16 [dir][8192][2048]
    gemm_k<128, 128, 4, 4, 0><<<dim3(16, 64, 2), 256, 0, stream>>>(
        xn, 512, DMODEL, win, win + 2048 * 512, 512,
        xz, (long)MROWS * 2048, 2048, nullptr, 0, nullptr, nullptr, 512);

    conv_silu_kernel<<<1024, 256, 0, stream>>>(xz, xc, cwF, cbF, cwB, cbB);

    // x_proj: [8192,1024] x [64,1024]^T -> x_dbl f32 + bf16 shadow
    gemm_k<64, 64, 2, 2, 1><<<dim3(1, 128, 2), 256, 0, stream>>>(
        xc, (long)MROWS * 1024, 1024, wxp, wxp + 64 * 1024, 1024,
        xdbl, (long)MROWS * 64, 64, xdbl_bf, (long)MROWS * 64, nullptr, nullptr, 1024);

    // dt_proj: [8192,32] x [1024,32]^T -> softplus(+bias) f32
    gemm_k<128, 128, 4, 4, 2><<<dim3(8, 64, 2), 256, 0, stream>>>(
        xdbl_bf, (long)MROWS * 64, 64, wdt, wdt + 1024 * 32, 32,
        dt, (long)MROWS * 1024, 1024, nullptr, 0, dtbF, dtbB, 32);

    // chunked scan: 128 chunks x 32 steps, lane = channel
    scan_part1<<<dim3(4, SCH, 4), 256, 0, stream>>>(dt, xc, xdbl, hend, sdt, AlF, AlB);
    scan_part2<<<256, 256, 0, stream>>>(hend, sdt, AlF, AlB);
    scan_part3<<<dim3(4, SCH, 4), 256, 0, stream>>>(dt, xc, xdbl, xz, hend, yg,
                                                    AlF, AlB, DF, DB);

    // out_proj + residual: [8192,1024] x [512,1024]^T -> d_out[row][dir*512+col]
    gemm_k<128, 128, 4, 4, 3><<<dim3(4, 64, 2), 256, 0, stream>>>(
        yg, (long)MROWS * 1024, 1024, wop, wop + 512 * 1024, 1024,
        d_out, 512, 1024, nullptr, 0, x, nullptr, 1024);
}

// Round 7
// 419.221 us; speedup vs baseline: 7.8788x; 1.0000x over previous
//
#include <hip/hip_runtime.h>
#include <hip/hip_bf16.h>
#include <cstdint>

#define DMODEL 1024
#define DHALF  512
#define DINNER 1024
#define DSTATE 16
#define DTRANK 32
#define LSEQ   4096
#define BBATCH 2
#define MROWS  (BBATCH*LSEQ)   // 8192
#define SCH    128             // scan chunks
#define SCT    32              // steps per chunk (SCH*SCT == LSEQ)

using bf16 = __bf16;
using bf16x8 = __attribute__((ext_vector_type(8))) __bf16;
using f32x4  = __attribute__((ext_vector_type(4))) float;
using f32x2  = __attribute__((ext_vector_type(2))) float;

__device__ __forceinline__ float sigmoidf_(float x) { return 1.f / (1.f + __expf(-x)); }
__device__ __forceinline__ float softplusf_(float x) { return fmaxf(x, 0.f) + log1pf(__expf(-fabsf(x))); }

// async global->LDS, 16B per lane; LDS dest = wave-uniform base + lane*16
__device__ __forceinline__ void glds16(const bf16* g, bf16* l) {
    __builtin_amdgcn_global_load_lds(
        (const __attribute__((address_space(1))) void*)g,
        (__attribute__((address_space(3))) void*)l, 16, 0, 0);
}

// ---------------------------------------------------------------- LayerNorm
__global__ __launch_bounds__(256) void ln_kernel(
    const float* __restrict__ x, const float* __restrict__ w,
    const float* __restrict__ b, bf16* __restrict__ xn)
{
    const int row = blockIdx.x;
    const int tid = threadIdx.x;
    const float4 v = *(const float4*)&x[(size_t)row * DMODEL + tid * 4];
    float s  = v.x + v.y + v.z + v.w;
    float s2 = v.x * v.x + v.y * v.y + v.z * v.z + v.w * v.w;
#pragma unroll
    for (int off = 1; off < 64; off <<= 1) {
        s  += __shfl_xor(s, off);
        s2 += __shfl_xor(s2, off);
    }
    __shared__ float red[8];
    const int wid = tid >> 6;
    if ((tid & 63) == 0) { red[wid] = s; red[4 + wid] = s2; }
    __syncthreads();
    s  = red[0] + red[1] + red[2] + red[3];
    s2 = red[4] + red[5] + red[6] + red[7];
    const float mu   = s * (1.f / DMODEL);
    const float var  = s2 * (1.f / DMODEL) - mu * mu;
    const float rstd = rsqrtf(var + 1e-5f);
    const float4 wv = *(const float4*)&w[tid * 4];
    const float4 bv = *(const float4*)&b[tid * 4];
    union { bf16 o[4]; uint2 u; } pk;
    pk.o[0] = (bf16)((v.x - mu) * rstd * wv.x + bv.x);
    pk.o[1] = (bf16)((v.y - mu) * rstd * wv.y + bv.y);
    pk.o[2] = (bf16)((v.z - mu) * rstd * wv.z + bv.z);
    pk.o[3] = (bf16)((v.w - mu) * rstd * wv.w + bv.w);
    *(uint2*)&xn[(size_t)row * DMODEL + tid * 4] = pk.u;
}

// ------------------------------------------------------- weight fp32->bf16
__global__ __launch_bounds__(256) void cvt_weights_kernel(
    const float* __restrict__ s0, const float* __restrict__ s1,
    const float* __restrict__ s2, const float* __restrict__ s3,
    const float* __restrict__ s4, const float* __restrict__ s5,
    const float* __restrict__ s6, const float* __restrict__ s7,
    bf16* __restrict__ d0, bf16* __restrict__ d1, bf16* __restrict__ d2,
    bf16* __restrict__ d3, bf16* __restrict__ d4, bf16* __restrict__ d5,
    bf16* __restrict__ d6, bf16* __restrict__ d7)
{
    const size_t gid = ((size_t)blockIdx.x * 256 + threadIdx.x) * 4;
    const float* s; bf16* dst; size_t off;
    if      (gid < 1048576) { s = s0; dst = d0; off = gid; }
    else if (gid < 2097152) { s = s1; dst = d1; off = gid - 1048576; }
    else if (gid < 2162688) { s = s2; dst = d2; off = gid - 2097152; }
    else if (gid < 2228224) { s = s3; dst = d3; off = gid - 2162688; }
    else if (gid < 2752512) { s = s4; dst = d4; off = gid - 2228224; }
    else if (gid < 3276800) { s = s5; dst = d5; off = gid - 2752512; }
    else if (gid < 3309568) { s = s6; dst = d6; off = gid - 3276800; }
    else if (gid < 3342336) { s = s7; dst = d7; off = gid - 3309568; }
    else return;
    const float4 v = *(const float4*)&s[off];
    union { bf16 o[4]; uint2 u; } pk;
    pk.o[0] = (bf16)v.x; pk.o[1] = (bf16)v.y; pk.o[2] = (bf16)v.z; pk.o[3] = (bf16)v.w;
    *(uint2*)&dst[off] = pk.u;
}

// ----------------------------------------------------------------- GEMM
// C[m,n] = sum_k A[m,k] * W[n,k]. m97 structure: global_load_lds(16B) into
// LINEAR LDS [rows][32], 2 barriers per K-step.
// EPI 0: bf16 store   1: f32+bf16 dual   2: softplus(v+bias[col]) f32
// EPI 3: v + residual f32
template<int BM, int BN, int WTM, int WTN, int EPI>
__global__ __launch_bounds__(256) void gemm_k(
    const bf16* __restrict__ A0, long aDirStride, int lda,
    const bf16* __restrict__ W0, const bf16* __restrict__ W1, int ldw,
    void* __restrict__ C0, long cDirStride, int ldc,
    void* __restrict__ C1, long c1DirStride,
    const float* __restrict__ X0, const float* __restrict__ X1,
    int K)
{
    constexpr int WGN = BN / (WTN * 16);
    static_assert((BM * 32) % 2048 == 0 && (BN * 32) % 2048 == 0, "tile");
    __shared__ alignas(16) bf16 As[BM * 32];
    __shared__ alignas(16) bf16 Bs[BN * 32];
    const int tid = threadIdx.x;
    const int wid = tid >> 6, lane = tid & 63;
    const int wr = wid / WGN, wc = wid % WGN;
    const int bx = blockIdx.x, by = blockIdx.y, bz = blockIdx.z;
    const bf16* A = A0 + (long)bz * aDirStride + (long)by * BM * lda;
    const bf16* W = (bz ? W1 : W0) + (long)bx * BN * ldw;
    f32x4 acc[WTM][WTN] = {};
    for (int k0 = 0; k0 < K; k0 += 32) {
        constexpr int AP = BM * 32 / 2048;
#pragma unroll
        for (int p = 0; p < AP; ++p) {
            const int idx = (p * 256 + tid) * 8;
            const int r = idx >> 5, c = idx & 31;
            glds16(&A[(long)r * lda + k0 + c], &As[p * 2048 + wid * 512]);
        }
        constexpr int BP = BN * 32 / 2048;
#pragma unroll
        for (int p = 0; p < BP; ++p) {
            const int idx = (p * 256 + tid) * 8;
            const int r = idx >> 5, c = idx & 31;
            glds16(&W[(long)r * ldw + k0 + c], &Bs[p * 2048 + wid * 512]);
        }
        __syncthreads();
        const int rA = lane & 15, kO = (lane >> 4) * 8;
        bf16x8 af[WTM], bw[WTN];
#pragma unroll
        for (int i = 0; i < WTM; ++i)
            af[i] = *(const bf16x8*)&As[(wr * WTM * 16 + i * 16 + rA) * 32 + kO];
#pragma unroll
        for (int j = 0; j < WTN; ++j)
            bw[j] = *(const bf16x8*)&Bs[(wc * WTN * 16 + j * 16 + rA) * 32 + kO];
#pragma unroll
        for (int i = 0; i < WTM; ++i)
#pragma unroll
            for (int j = 0; j < WTN; ++j)
                acc[i][j] = __builtin_amdgcn_mfma_f32_16x16x32_bf16(af[i], bw[j], acc[i][j], 0, 0, 0);
        __syncthreads();
    }
    const int rl = (lane >> 4) * 4, cl = lane & 15;
    const int rowBase = by * BM + wr * WTM * 16;
    const int colBase = bx * BN + wc * WTN * 16;
#pragma unroll
    for (int i = 0; i < WTM; ++i)
#pragma unroll
        for (int j = 0; j < WTN; ++j) {
#pragma unroll
            for (int r = 0; r < 4; ++r) {
                const int row = rowBase + i * 16 + rl + r;
                const int col = colBase + j * 16 + cl;
                const float v = acc[i][j][r];
                if constexpr (EPI == 0) {
                    ((bf16*)C0 + (long)bz * cDirStride)[(long)row * ldc + col] = (bf16)v;
                } else if constexpr (EPI == 1) {
                    ((float*)C0 + (long)bz * cDirStride)[(long)row * ldc + col] = v;
                    ((bf16*)C1 + (long)bz * c1DirStride)[(long)row * ldc + col] = (bf16)v;
                } else if constexpr (EPI == 2) {
                    const float* bias = bz ? X1 : X0;
                    ((float*)C0 + (long)bz * cDirStride)[(long)row * ldc + col] =
                        softplusf_(v + bias[col]);
                } else {
                    const long idx = (long)row * ldc + col;
                    ((float*)C0 + (long)bz * cDirStride)[idx] = v + (X0 + (long)bz * cDirStride)[idx];
                }
            }
        }
}

// --------------------------------------------------- depthwise conv4 + SiLU
// thread = 8 channels x 8 timesteps, rolling window.
#define CT 8
__global__ __launch_bounds__(256) void conv_silu_kernel(
    const bf16* __restrict__ xz, bf16* __restrict__ xc,
    const float* __restrict__ cwF, const float* __restrict__ cbF,
    const float* __restrict__ cwB, const float* __restrict__ cbB)
{
    const size_t gid = (size_t)blockIdx.x * 256 + threadIdx.x; // 2^18
    const int g = (int)(gid & 127);            // channel group (8 ch)
    const int tt = (int)((gid >> 7) & (LSEQ / CT - 1));
    const int b = (int)((gid >> 16) & 1);
    const int dir = (int)(gid >> 17);          // wave-uniform
    const int d0 = g * 8;
    const float* cw = dir ? cwB : cwF;
    const float* cb = dir ? cbB : cbF;
    float bias[8];
#pragma unroll
    for (int e = 0; e < 8; e += 4) *(float4*)&bias[e] = *(const float4*)&cb[d0 + e];
    float4 wv[8];
#pragma unroll
    for (int e = 0; e < 8; ++e) wv[e] = *(const float4*)&cw[(d0 + e) * 4];
    const int t0 = tt * CT;
    const size_t rowBase = (size_t)dir * MROWS * 2048 + (size_t)b * LSEQ * 2048;
    const bf16* src = xz + rowBase + d0;
    bf16* dst = xc + (size_t)dir * MROWS * DINNER + (size_t)b * LSEQ * DINNER
                + (size_t)t0 * DINNER + d0;

    float w0[8] = {}, w1[8] = {}, w2[8] = {};
    auto loadRow = [&](int ts, float* r) {
        if (ts >= 0 && ts < LSEQ) {
            const bf16x8 v = *(const bf16x8*)&src[(size_t)ts * 2048];
#pragma unroll
            for (int e = 0; e < 8; ++e) r[e] = (float)v[e];
        } else {
#pragma unroll
            for (int e = 0; e < 8; ++e) r[e] = 0.f;
        }
    };
    if (!dir) { loadRow(t0 - 3, w0); loadRow(t0 - 2, w1); loadRow(t0 - 1, w2); }
    else      { loadRow(t0,     w0); loadRow(t0 + 1, w1); loadRow(t0 + 2, w2); }

#pragma unroll
    for (int i = 0; i < CT; ++i) {
        float w3[8];
        loadRow(dir ? (t0 + i + 3) : (t0 + i), w3);
        bf16x8 o;
        if (!dir) {
#pragma unroll
            for (int e = 0; e < 8; ++e) {
                float acc = bias[e];
                acc = fmaf(wv[e].x, w0[e], acc);
                acc = fmaf(wv[e].y, w1[e], acc);
                acc = fmaf(wv[e].z, w2[e], acc);
                acc = fmaf(wv[e].w, w3[e], acc);
                const float s = acc * sigmoidf_(acc);
                o[e] = (bf16)s;
            }
        } else {
#pragma unroll
            for (int e = 0; e < 8; ++e) {
                float acc = bias[e];
                acc = fmaf(wv[e].w, w0[e], acc);
                acc = fmaf(wv[e].z, w1[e], acc);
                acc = fmaf(wv[e].y, w2[e], acc);
                acc = fmaf(wv[e].x, w3[e], acc);
                const float s = acc * sigmoidf_(acc);
                o[e] = (bf16)s;
            }
        }
        *(bf16x8*)&dst[(size_t)i * DINNER] = o;
#pragma unroll
        for (int e = 0; e < 8; ++e) { w0[e] = w1[e]; w1[e] = w2[e]; w2[e] = w3[e]; }
    }
}

// ------------------------------------------------- chunked selective scan
// lane = one channel d; 16 states in registers as 8 x float2 (v_pk_* ops).
// Fast path exploits a[n] == -(n+1): dA[n] = q^(n+1), q = exp(-dt).
// B/C rows indexed by wave-uniform expressions -> scalar (SMEM) loads.
__global__ __launch_bounds__(256) void scan_part1(
    const float* __restrict__ dt, const bf16* __restrict__ xc,
    const float* __restrict__ xdbl,
    float* __restrict__ hend, float* __restrict__ sdtOut,
    const float* __restrict__ AlogF, const float* __restrict__ AlogB)
{
    const int d = blockIdx.x * 256 + threadIdx.x;
    const int chunk = blockIdx.y;
    const int sb = blockIdx.z;
    const int dir = sb >> 1, b = sb & 1;
    const float* Alog = dir ? AlogB : AlogF;
    float a[16];
#pragma unroll
    for (int n = 0; n < 16; n += 4)
        *(float4*)&a[n] = *(const float4*)&Alog[d * 16 + n];
#pragma unroll
    for (int n = 0; n < 16; ++n) a[n] = -__expf(a[n]);
    bool fast = true;
#pragma unroll
    for (int n = 0; n < 16; ++n) fast = fast && (fabsf(a[n] + (float)(n + 1)) <= 1e-3f * (n + 1));
    const size_t base1 = (size_t)dir * MROWS * DINNER + (size_t)b * LSEQ * DINNER;
    const size_t base64 = (size_t)dir * MROWS * 64 + (size_t)b * LSEQ * 64;
    const int t0 = dir ? (LSEQ - 1) : 0;
    const int stp = dir ? -1 : 1;
    const int ts = t0 + stp * (chunk * SCT);
    const float* pdt = dt + base1 + (size_t)ts * DINNER + d;
    const bf16* pxc = xc + base1 + (size_t)ts * DINNER + d;
    const float* xb = xdbl + base64 + 32;      // uniform base for B rows
    const long s1 = (long)stp * DINNER;
    float sacc = 0.f;
    f32x2 h2[8];
#pragma unroll
    for (int j = 0; j < 8; ++j) h2[j] = (f32x2){0.f, 0.f};
    if (fast) {
#pragma unroll 4
        for (int i = 0; i < SCT; ++i) {
            const float dtv = *pdt;
            const float u = (float)*pxc;
            const float dtu = dtv * u;
            sacc += dtv;
            const float* bRow = xb + (size_t)(ts + stp * i) * 64;   // uniform
            const float q = __expf(-dtv);
            const float q2 = q * q;
            const f32x2 qq = {q2, q2};
            f32x2 p = {q, q2};
#pragma unroll
            for (int j = 0; j < 8; ++j) {
                const f32x2 B2 = *(const f32x2*)&bRow[2 * j];
                const f32x2 b2 = B2 * dtu;
                h2[j] = __builtin_elementwise_fma(h2[j], p, b2);
                p = p * qq;
            }
            pdt += s1; pxc += s1;
        }
    } else {
#pragma unroll 4
        for (int i = 0; i < SCT; ++i) {
            const float dtv = *pdt;
            const float u = (float)*pxc;
            const float dtu = dtv * u;
            sacc += dtv;
            const float* bRow = xb + (size_t)(ts + stp * i) * 64;
#pragma unroll
            for (int j = 0; j < 8; ++j) {
                const f32x2 B2 = *(const f32x2*)&bRow[2 * j];
                const f32x2 dA = {__expf(dtv * a[2 * j]), __expf(dtv * a[2 * j + 1])};
                h2[j] = __builtin_elementwise_fma(h2[j], dA, B2 * dtu);
            }
            pdt += s1; pxc += s1;
        }
    }
    const size_t o = ((size_t)sb * SCH + chunk) * 16384 + (size_t)d * 16;
#pragma unroll
    for (int j = 0; j < 8; ++j) *(f32x2*)&hend[o + 2 * j] = h2[j];
    sdtOut[((size_t)sb * SCH + chunk) * 1024 + d] = sacc;
}

// combine chunk summaries across chunks; hend[c] becomes h_in for chunk c.
__global__ __launch_bounds__(256) void scan_part2(
    float* __restrict__ hend, const float* __restrict__ sdt,
    const float* __restrict__ AlogF, const float* __restrict__ AlogB)
{
    const size_t gid = (size_t)blockIdx.x * 256 + threadIdx.x;  // 65536
    const int sb = (int)(gid >> 14);
    const int dn = (int)(gid & 16383);
    const int d = dn >> 4;
    const float* Alog = (sb >> 1) ? AlogB : AlogF;
    const float a_n = -__expf(Alog[dn]);
    float h = 0.f;
    size_t idx = (size_t)sb * SCH * 16384 + dn;
    size_t sidx = (size_t)sb * SCH * 1024 + d;
#pragma unroll 4
    for (int c = 0; c < SCH; ++c) {
        const float sd = sdt[sidx];
        const float pe = __expf(a_n * sd);
        const float he = hend[idx];
        hend[idx] = h;
        h = fmaf(pe, h, he);
        idx += 16384; sidx += 1024;
    }
}

// final pass: chunk scan from h_in; y = sum_n h*C; gate with silu(z)
__global__ __launch_bounds__(256) void scan_part3(
    const float* __restrict__ dt, const bf16* __restrict__ xc,
    const float* __restrict__ xdbl, const bf16* __restrict__ xz,
    const float* __restrict__ hin, bf16* __restrict__ yg,
    const float* __restrict__ AlogF, const float* __restrict__ AlogB,
    const float* __restrict__ DF, const float* __restrict__ DB)
{
    const int d = blockIdx.x * 256 + threadIdx.x;
    const int chunk = blockIdx.y;
    const int sb = blockIdx.z;
    const int dir = sb >> 1, b = sb & 1;
    const float* Alog = dir ? AlogB : AlogF;
    const float* Dw = dir ? DB : DF;
    float a[16];
#pragma unroll
    for (int n = 0; n < 16; n += 4)
        *(float4*)&a[n] = *(const float4*)&Alog[d * 16 + n];
#pragma unroll
    for (int n = 0; n < 16; ++n) a[n] = -__expf(a[n]);
    bool fast = true;
#pragma unroll
    for (int n = 0; n < 16; ++n) fast = fast && (fabsf(a[n] + (float)(n + 1)) <= 1e-3f * (n + 1));
    const float Dv = Dw[d];
    const size_t base1 = (size_t)dir * MROWS * DINNER + (size_t)b * LSEQ * DINNER;
    const size_t base64 = (size_t)dir * MROWS * 64 + (size_t)b * LSEQ * 64;
    const size_t baseZ = (size_t)dir * MROWS * 2048 + (size_t)b * LSEQ * 2048;
    const int t0 = dir ? (LSEQ - 1) : 0;
    const int stp = dir ? -1 : 1;
    const int ts = t0 + stp * (chunk * SCT);
    const float* pdt = dt + base1 + (size_t)ts * DINNER + d;
    const bf16* pxc = xc + base1 + (size_t)ts * DINNER + d;
    const float* xb = xdbl + base64 + 32;      // uniform base: B at +0, C at +16
    const bf16* pz = xz + baseZ + (size_t)ts * 2048 + 1024 + d;
    bf16* pyg = yg + base1 + (size_t)ts * DINNER + d;
    const long s1 = (long)stp * DINNER, sZ = (long)stp * 2048;
    f32x2 h2[8];
    const size_t o = ((size_t)sb * SCH + chunk) * 16384 + (size_t)d * 16;
#pragma unroll
    for (int j = 0; j < 8; ++j) h2[j] = *(const f32x2*)&hin[o + 2 * j];
    if (fast) {
#pragma unroll 4
        for (int i = 0; i < SCT; ++i) {
            const float dtv = *pdt;
            const float u = (float)*pxc;
            const float dtu = dtv * u;
            const float* bRow = xb + (size_t)(ts + stp * i) * 64;   // uniform
            const float q = __expf(-dtv);
            const float q2 = q * q;
            const f32x2 qq = {q2, q2};
            f32x2 p = {q, q2};
            f32x2 y2 = {0.f, 0.f};
#pragma unroll
            for (int j = 0; j < 8; ++j) {
                const f32x2 B2 = *(const f32x2*)&bRow[2 * j];
                const f32x2 C2 = *(const f32x2*)&bRow[16 + 2 * j];
                h2[j] = __builtin_elementwise_fma(h2[j], p, B2 * dtu);
                y2 = __builtin_elementwise_fma(h2[j], C2, y2);
                p = p * qq;
            }
            const float y = y2[0] + y2[1];
            const float z = (float)*pz;
            const float out = (y + Dv * u) * (z * sigmoidf_(z));
            *pyg = (bf16)out;
            pdt += s1; pxc += s1; pz += sZ; pyg += s1;
        }
    } else {
#pragma unroll 4
        for (int i = 0; i < SCT; ++i) {
            const float dtv = *pdt;
            const float u = (float)*pxc;
            const float dtu = dtv * u;
            const float* bRow = xb + (size_t)(ts + stp * i) * 64;
            f32x2 y2 = {0.f, 0.f};
#pragma unroll
            for (int j = 0; j < 8; ++j) {
                const f32x2 B2 = *(const f32x2*)&bRow[2 * j];
                const f32x2 C2 = *(const f32x2*)&bRow[16 + 2 * j];
                const f32x2 dA = {__expf(dtv * a[2 * j]), __expf(dtv * a[2 * j + 1])};
                h2[j] = __builtin_elementwise_fma(h2[j], dA, B2 * dtu);
                y2 = __builtin_elementwise_fma(h2[j], C2, y2);
            }
            const float y = y2[0] + y2[1];
            const float z = (float)*pz;
            const float out = (y + Dv * u) * (z * sigmoidf_(z));
            *pyg = (bf16)out;
            pdt += s1; pxc += s1; pz += sZ; pyg += s1;
        }
    }
}

// ------------------------------------------------------------------- launch
extern "C" void kernel_launch(void* const* d_in, const int* in_sizes, int n_in,
                              void* d_out, int out_size, void* d_ws, size_t ws_size,
                              hipStream_t stream)
{
    const float* x      = (const float*)d_in[0];
    const float* norm_w = (const float*)d_in[1];
    const float* norm_b = (const float*)d_in[2];
    const float* ipF  = (const float*)d_in[3];
    const float* cwF  = (const float*)d_in[4];
    const float* cbF  = (const float*)d_in[5];
    const float* xpF  = (const float*)d_in[6];
    const float* dtwF = (const float*)d_in[7];
    const float* dtbF = (const float*)d_in[8];
    const float* AlF  = (const float*)d_in[9];
    const float* DF   = (const float*)d_in[10];
    const float* opF  = (const float*)d_in[11];
    const float* ipB  = (const float*)d_in[12];
    const float* cwB  = (const float*)d_in[13];
    const float* cbB  = (const float*)d_in[14];
    const float* xpB  = (const float*)d_in[15];
    const float* dtwB = (const float*)d_in[16];
    const float* dtbB = (const float*)d_in[17];
    const float* AlB  = (const float*)d_in[18];
    const float* DB   = (const float*)d_in[19];
    const float* opB  = (const float*)d_in[20];

    char* ws = (char*)d_ws;
    size_t off = 0;
    auto alloc = [&](size_t bytes) -> void* {
        void* p = ws + off;
        off += (bytes + 255) & ~(size_t)255;
        return p;
    };
    bf16*  xn      = (bf16*)alloc((size_t)MROWS * DMODEL * 2);
    bf16*  win     = (bf16*)alloc((size_t)2 * 2048 * 512 * 2);
    bf16*  wxp     = (bf16*)alloc((size_t)2 * 64 * 1024 * 2);
    bf16*  wop     = (bf16*)alloc((size_t)2 * 512 * 1024 * 2);
    bf16*  wdt     = (bf16*)alloc((size_t)2 * 1024 * 32 * 2);
    bf16*  xz      = (bf16*)alloc((size_t)2 * MROWS * 2048 * 2);
    bf16*  xc      = (bf16*)alloc((size_t)2 * MROWS * 1024 * 2);
    float* xdbl    = (float*)alloc((size_t)2 * MROWS * 64 * 4);
    bf16*  xdbl_bf = (bf16*)alloc((size_t)2 * MROWS * 64 * 2);
    float* dt      = (float*)alloc((size_t)2 * MROWS * 1024 * 4);
    bf16*  yg      = (bf16*)alloc((size_t)2 * MROWS * 1024 * 2);
    float* hend    = (float*)alloc((size_t)4 * SCH * 16384 * 4);
    float* sdt     = (float*)alloc((size_t)4 * SCH * 1024 * 4);

    cvt_weights_kernel<<<3264, 256, 0, stream>>>(
        ipF, ipB, xpF, xpB, opF, opB, dtwF, dtwB,
        win, win + 2048 * 512, wxp, wxp + 64 * 1024,
        wop, wop + 512 * 1024, wdt, wdt + 1024 * 32);

    ln_kernel<<<MROWS, 256, 0, stream>>>(x, norm_w, norm_b, xn);

    // in_proj: [8192,512] x [2048,512]^T -> xz bf16 [dir][8192][2048]
    gemm_k<128, 128, 4, 4, 0><<<dim3(16, 64, 2), 256, 0, stream>>>(
        xn, 512, DMODEL, win, win + 2048 * 512, 512,
        xz, (long)MROWS * 2048, 2048, nullptr, 0, nullptr, nullptr, 512);

    conv_silu_kernel<<<1024, 256, 0, stream>>>(xz, xc, cwF, cbF, cwB, cbB);

    // x_proj: [8192,1024] x [64,1024]^T -> x_dbl f32 + bf16 shadow
    gemm_k<64, 64, 2, 2, 1><<<dim3(1, 128, 2), 256, 0, stream>>>(
        xc, (long)MROWS * 1024, 1024, wxp, wxp + 64 * 1024, 1024,
        xdbl, (long)MROWS * 64, 64, xdbl_bf, (long)MROWS * 64, nullptr, nullptr, 1024);

    // dt_proj: [8192,32] x [1024,32]^T -> softplus(+bias) f32
    gemm_k<128, 128, 4, 4, 2><<<dim3(8, 64, 2), 256, 0, stream>>>(
        xdbl_bf, (long)MROWS * 64, 64, wdt, wdt + 1024 * 32, 32,
        dt, (long)MROWS * 1024, 1024, nullptr, 0, dtbF, dtbB, 32);

    // chunked scan: 128 chunks x 32 steps, lane = channel
    scan_part1<<<dim3(4, SCH, 4), 256, 0, stream>>>(dt, xc, xdbl, hend, sdt, AlF, AlB);
    scan_part2<<<256, 256, 0, stream>>>(hend, sdt, AlF, AlB);
    scan_part3<<<dim3(4, SCH, 4), 256, 0, stream>>>(dt, xc, xdbl, xz, hend, yg,
                                                    AlF, AlB, DF, DB);

    // out_proj + residual: [8192,1024] x [512,1024]^T -> d_out[row][dir*512+col]
    gemm_k<128, 128, 4, 4, 3><<<dim3(4, 64, 2), 256, 0, stream>>>(
        yg, (long)MROWS * 1024, 1024, wop, wop + 512 * 1024, 1024,
        d_out, 512, 1024, nullptr, 0, x, nullptr, 1024);
}